// Round 13
// baseline (1651.472 us; speedup 1.0000x reference)
//
#include <hip/hip_runtime.h>
#include <math.h>

#define NNODE 10000
#define INCH  9998
#define NEDGE 320000
#define CHWP  12288        // Wimg chunk stride (halves)
#define WSLOT 10880        // live halves per W chunk (2*80*68)
#define XSTR  66           // x LDS row stride (floats)
#define ZN    1000064      // floats in the contiguous zero block [xl1..gat2]

typedef _Float16 half8 __attribute__((ext_vector_type(8)));
typedef float    f32x4 __attribute__((ext_vector_type(4)));

__device__ __forceinline__ float lrelu(float v){ return v > 0.f ? v : 0.2f*v; }
__device__ __forceinline__ float frelu(float v){ return v > 0.f ? v : 0.f; }

#define GLOAD_LDS16(g, l) __builtin_amdgcn_global_load_lds( \
    (const __attribute__((address_space(1))) unsigned int*)(g), \
    (__attribute__((address_space(3))) unsigned int*)(l), 16, 0, 0)
#define GLOAD_LDS4(g, l) __builtin_amdgcn_global_load_lds( \
    (const __attribute__((address_space(1))) unsigned int*)(g), \
    (__attribute__((address_space(3))) unsigned int*)(l), 4, 0, 0)

// ---------------------------------------------------------------------------
__global__ void prep_wt(const float* __restrict__ Wl, const float* __restrict__ Wr,
                        const float* __restrict__ We, _Float16* __restrict__ Wimg,
                        float* __restrict__ zblk){
  int idx = blockIdx.x*256 + threadIdx.x;
  if (idx < ZN) zblk[idx] = 0.f;
  if (idx >= 160*CHWP) return;
  int ci   = idx / CHWP;
  int rem  = idx - ci*CHWP;
  float v = 0.f;
  int valid = 0;
  if (rem < WSLOT){
    int sp   = rem / 5440;
    int rem2 = rem - sp*5440;
    int col  = rem2 / 68;
    int k68  = rem2 - col*68;
    int k    = ci*64 + k68;
    if (k68 < 64 && k < INCH){
      v = (col < 8) ? Wl[k*8 + col] : (col < 16 ? Wr[k*8 + (col-8)] : We[k*64 + (col-16)]);
      valid = sp + 1;
    }
  }
  _Float16 h = (_Float16)v;
  Wimg[idx] = (valid == 2) ? (_Float16)((v - (float)h) * 2048.f) : h;
}

// ---------------------------------------------------------------------------
// r13: ABLATION round. template<MODE> bits: 1=W-stage, 2=x-stage, 4=compute,
// 8=barrier. Real kernel = 15. Clones 14(noW),13(noX),11(noC),7(noB) write to
// dead scratch — their per-dispatch dur_us isolates which phase owns the
// ~14K cycles/chunk that six structural rewrites (r7-r12) failed to move.
#define TILE(T, AH, AL, LB, KOFF, H, L) { \
  half8 bh = *(const half8*)((LB) + (16*(T)+c0)*68 + (KOFF)); \
  half8 bl = *(const half8*)((LB) + 5440 + (16*(T)+c0)*68 + (KOFF)); \
  H = __builtin_amdgcn_mfma_f32_16x16x32_f16(AH, bh, H, 0, 0, 0); \
  L = __builtin_amdgcn_mfma_f32_16x16x32_f16(AH, bl, L, 0, 0, 0); \
  L = __builtin_amdgcn_mfma_f32_16x16x32_f16(AL, bh, L, 0, 0, 0); }

#define KSTEPL(S, XROWP, LBW) { \
  float4 xa_ = *(const float4*)((XROWP) + (S)*32 + g*8); \
  float4 xb_ = *(const float4*)((XROWP) + (S)*32 + g*8 + 4); \
  _Float16 h0_=(_Float16)xa_.x, h1_=(_Float16)xa_.y, h2_=(_Float16)xa_.z, h3_=(_Float16)xa_.w; \
  _Float16 h4_=(_Float16)xb_.x, h5_=(_Float16)xb_.y, h6_=(_Float16)xb_.z, h7_=(_Float16)xb_.w; \
  half8 ah = {h0_,h1_,h2_,h3_,h4_,h5_,h6_,h7_}; \
  half8 al = {(_Float16)((xa_.x-(float)h0_)*2048.f), (_Float16)((xa_.y-(float)h1_)*2048.f), \
              (_Float16)((xa_.z-(float)h2_)*2048.f), (_Float16)((xa_.w-(float)h3_)*2048.f), \
              (_Float16)((xb_.x-(float)h4_)*2048.f), (_Float16)((xb_.y-(float)h5_)*2048.f), \
              (_Float16)((xb_.z-(float)h6_)*2048.f), (_Float16)((xb_.w-(float)h7_)*2048.f)}; \
  TILE(0, ah, al, LBW, (S)*32 + g*8, ach0, acl0) \
  TILE(1, ah, al, LBW, (S)*32 + g*8, ach1, acl1) \
  TILE(2, ah, al, LBW, (S)*32 + g*8, ach2, acl2) \
  TILE(3, ah, al, LBW, (S)*32 + g*8, ach3, acl3) \
  TILE(4, ah, al, LBW, (S)*32 + g*8, ach4, acl4) }

#define STAGE_W(CI, DST) { \
  const _Float16* wsrc_ = Wimg + (size_t)(CI)*CHWP; \
  _Pragma("unroll") \
  for (int i_ = 0; i_ < 6; ++i_){ \
    int seg_ = wv + 4*i_; \
    if (seg_ < 21)       GLOAD_LDS16(wsrc_ + seg_*512 + lane*8, (DST) + seg_*512); \
    else if (seg_ == 21) GLOAD_LDS4 (wsrc_ + seg_*512 + lane*2, (DST) + seg_*512); \
  } }

#define STAGE_X(K0, DB) { \
  _Pragma("unroll") \
  for (int r_ = 0; r_ < 16; ++r_){ \
    int lrow_ = wv*16 + r_; \
    int grow_ = rb*64 + lrow_; if (grow_ > NNODE-1) grow_ = NNODE-1; \
    size_t so_ = (size_t)grow_*INCH + (size_t)(K0); \
    if (so_ > (size_t)NNODE*INCH - 64) so_ = (size_t)NNODE*INCH - 64; \
    GLOAD_LDS4(x + so_ + lane, &ldsx[DB][lrow_*XSTR]); \
  } }

#define EPI(T, H, L) { \
  int col = 16*(T) + c0; \
  float v0 = H[0] + L[0]*inv2048; \
  float v1 = H[1] + L[1]*inv2048; \
  float v2 = H[2] + L[2]*inv2048; \
  float v3 = H[3] + L[3]*inv2048; \
  if (kh == 0){ \
    float bb = (col < 8) ? bl1[col] : (col < 16 ? br1[col-8] : 0.f); \
    v0 += bb; v1 += bb; v2 += bb; v3 += bb; \
  } \
  float* dst; int st; \
  if (col < 8)       { dst = xl1 + nodeb*8 + col;        st = 8; } \
  else if (col < 16) { dst = xr1 + nodeb*8 + col - 8;    st = 8; } \
  else               { dst = encp + nodeb*64 + col - 16; st = 64; } \
  atomicAdd(dst,        v0); \
  atomicAdd(dst + st,   v1); \
  atomicAdd(dst + 2*st, v2); \
  atomicAdd(dst + 3*st, v3); }

template<int MODE>
__global__ __launch_bounds__(256, 2)
void k1_tmpl(const float* __restrict__ x, const _Float16* __restrict__ Wimg,
             const float* __restrict__ bl1, const float* __restrict__ br1,
             float* __restrict__ xl1, float* __restrict__ xr1,
             float* __restrict__ encp){
  __shared__ _Float16 ldsw[2*WSLOT];         // 43520 B
  __shared__ float    ldsx[2][64*XSTR];      // 33792 B
  const int tid  = threadIdx.x;
  const int lane = tid & 63;
  const int wv   = tid >> 6;
  const int g    = lane >> 4;
  const int c0   = lane & 15;
  const int bid  = blockIdx.x;          // 0..470
  const int kh   = bid / 157;
  const int rb   = bid - kh*157;
  const int ci0  = (kh == 0) ? 0 : (kh == 1 ? 54 : 107);
  const int nch  = (kh == 0) ? 54 : 53;
  const int k0b  = ci0*64;

  const int arow = rb*64 + wv*16 + c0;

  f32x4 ach0={0,0,0,0}, ach1={0,0,0,0}, ach2={0,0,0,0}, ach3={0,0,0,0}, ach4={0,0,0,0};
  f32x4 acl0={0,0,0,0}, acl1={0,0,0,0}, acl2={0,0,0,0}, acl3={0,0,0,0}, acl4={0,0,0,0};

  if constexpr (MODE & 1) STAGE_W(ci0, ldsw);
  if constexpr (MODE & 2) STAGE_X(k0b, 0);

  for (int c = 0; c < nch; ++c){
    const int cur = c & 1;
    if constexpr (MODE & 8) __syncthreads();

    if (c + 1 < nch){
      if constexpr (MODE & 1) STAGE_W(ci0 + c + 1, ldsw + (cur^1)*WSLOT);
      if constexpr (MODE & 2) STAGE_X(k0b + (c+1)*64, cur^1);
    }

    if constexpr ((MODE & 6) == 6){
      const int k0c = k0b + c*64;
      if (arow == 9999 && k0c == 9984){
        #pragma unroll
        for (int j_ = 0; j_ < 16; ++j_){
          int kk = 9984 + g*16 + j_;
          float fv = (kk < INCH) ? x[(size_t)9999*INCH + kk] : 0.f;
          ldsx[cur][15*XSTR + g*16 + j_] = fv;
        }
      }
    }

    if constexpr (MODE & 4){
      const _Float16* lbw  = ldsw + cur*WSLOT;
      const float*    xrow = &ldsx[cur][(wv*16 + c0)*XSTR];
      KSTEPL(0, xrow, lbw)
      KSTEPL(1, xrow, lbw)
    }
  }

  const float inv2048 = 4.8828125e-4f;
  const int nodeb = rb*64 + wv*16 + 4*g;
  if (nodeb + 3 < NNODE){
    EPI(0, ach0, acl0) EPI(1, ach1, acl1) EPI(2, ach2, acl2)
    EPI(3, ach3, acl3) EPI(4, ach4, acl4)
  } else {
    #define EPIG(T, H, L) { \
      int col = 16*(T) + c0; \
      float b0 = (kh==0) ? ((col<8)?bl1[col]:(col<16?br1[col-8]:0.f)) : 0.f; \
      float vv0 = H[0] + L[0]*inv2048 + b0; \
      float vv1 = H[1] + L[1]*inv2048 + b0; \
      float vv2 = H[2] + L[2]*inv2048 + b0; \
      float vv3 = H[3] + L[3]*inv2048 + b0; \
      int base; float* dst; int st; \
      if (col < 8)       { dst = xl1;  base = col;      st = 8; } \
      else if (col < 16) { dst = xr1;  base = col - 8;  st = 8; } \
      else               { dst = encp; base = col - 16; st = 64; } \
      if (nodeb     < NNODE) atomicAdd(dst + (nodeb  )*st + base, vv0); \
      if (nodeb + 1 < NNODE) atomicAdd(dst + (nodeb+1)*st + base, vv1); \
      if (nodeb + 2 < NNODE) atomicAdd(dst + (nodeb+2)*st + base, vv2); \
      if (nodeb + 3 < NNODE) atomicAdd(dst + (nodeb+3)*st + base, vv3); }
    EPIG(0, ach0, acl0) EPIG(1, ach1, acl1) EPIG(2, ach2, acl2)
    EPIG(3, ach3, acl3) EPIG(4, ach4, acl4)
  }
}

// ---------------------------------------------------------------------------
__global__ void edgeA1(const int* __restrict__ ei, const float* __restrict__ xl,
                       const float* __restrict__ xr, const float* __restrict__ att,
                       float* __restrict__ elog, float* __restrict__ denom){
  int e = blockIdx.x*blockDim.x + threadIdx.x;
  if (e >= NEDGE + NNODE) return;
  int sN, dN;
  if (e < NEDGE) { sN = ei[e]; dN = ei[NEDGE + e]; } else { sN = dN = e - NEDGE; }
  const float4 a0 = *(const float4*)(xl + sN*8);
  const float4 a1 = *(const float4*)(xl + sN*8 + 4);
  const float4 b0 = *(const float4*)(xr + dN*8);
  const float4 b1 = *(const float4*)(xr + dN*8 + 4);
  float l0 = att[0]*lrelu(a0.x+b0.x) + att[1]*lrelu(a0.y+b0.y)
           + att[2]*lrelu(a0.z+b0.z) + att[3]*lrelu(a0.w+b0.w);
  float l1 = att[4]*lrelu(a1.x+b1.x) + att[5]*lrelu(a1.y+b1.y)
           + att[6]*lrelu(a1.z+b1.z) + att[7]*lrelu(a1.w+b1.w);
  float e0 = expf(l0), e1 = expf(l1);
  elog[e*2]   = e0;
  elog[e*2+1] = e1;
  atomicAdd(denom + dN*2,     e0);
  atomicAdd(denom + dN*2 + 1, e1);
}

__global__ void edgeB1(const int* __restrict__ ei, const float* __restrict__ elog,
                       const float* __restrict__ denom, const float* __restrict__ xl,
                       float* __restrict__ gat){
  int e = blockIdx.x*blockDim.x + threadIdx.x;
  if (e >= NEDGE + NNODE) return;
  int sN, dN;
  if (e < NEDGE) { sN = ei[e]; dN = ei[NEDGE + e]; } else { sN = dN = e - NEDGE; }
  float al0 = elog[e*2]   / denom[dN*2];
  float al1 = elog[e*2+1] / denom[dN*2 + 1];
  const float4 a0 = *(const float4*)(xl + sN*8);
  const float4 a1 = *(const float4*)(xl + sN*8 + 4);
  atomicAdd(gat + dN*8 + 0, a0.x*al0);
  atomicAdd(gat + dN*8 + 1, a0.y*al0);
  atomicAdd(gat + dN*8 + 2, a0.z*al0);
  atomicAdd(gat + dN*8 + 3, a0.w*al0);
  atomicAdd(gat + dN*8 + 4, a1.x*al1);
  atomicAdd(gat + dN*8 + 5, a1.y*al1);
  atomicAdd(gat + dN*8 + 6, a1.z*al1);
  atomicAdd(gat + dN*8 + 7, a1.w*al1);
}

__global__ void node_x1(const float* __restrict__ gat, const float* __restrict__ bias1,
                        const float* __restrict__ linW, const float* __restrict__ linb,
                        float* __restrict__ x1){
  int n = blockIdx.x*blockDim.x + threadIdx.x;
  if (n >= NNODE) return;
  float sacc = linb[0];
  #pragma unroll
  for (int c = 0; c < 8; ++c)
    sacc = fmaf(frelu(gat[n*8+c] + bias1[c]), linW[c], sacc);
  x1[n] = sacc;
}

__global__ void edgeA2(const int* __restrict__ ei, const float* __restrict__ x1,
                       const float* __restrict__ Wl2, const float* __restrict__ bl2,
                       const float* __restrict__ Wr2, const float* __restrict__ br2,
                       const float* __restrict__ att,
                       float* __restrict__ elog, float* __restrict__ denom){
  int e = blockIdx.x*blockDim.x + threadIdx.x;
  if (e >= NEDGE + NNODE) return;
  int sN, dN;
  if (e < NEDGE) { sN = ei[e]; dN = ei[NEDGE + e]; } else { sN = dN = e - NEDGE; }
  float xs = x1[sN], xd = x1[dN];
  float l0 = 0.f, l1 = 0.f;
  #pragma unroll
  for (int c = 0; c < 4; ++c) {
    l0 = fmaf(att[c],   lrelu(fmaf(xs, Wl2[c],   bl2[c])   + fmaf(xd, Wr2[c],   br2[c])),   l0);
    l1 = fmaf(att[4+c], lrelu(fmaf(xs, Wl2[4+c], bl2[4+c]) + fmaf(xd, Wr2[4+c], br2[4+c])), l1);
  }
  float e0 = expf(l0), e1 = expf(l1);
  elog[e*2]   = e0;
  elog[e*2+1] = e1;
  atomicAdd(denom + dN*2,     e0);
  atomicAdd(denom + dN*2 + 1, e1);
}

__global__ void edgeB2(const int* __restrict__ ei, const float* __restrict__ elog,
                       const float* __restrict__ denom, const float* __restrict__ x1,
                       const float* __restrict__ Wl2, const float* __restrict__ bl2,
                       float* __restrict__ gat){
  int e = blockIdx.x*blockDim.x + threadIdx.x;
  if (e >= NEDGE + NNODE) return;
  int sN, dN;
  if (e < NEDGE) { sN = ei[e]; dN = ei[NEDGE + e]; } else { sN = dN = e - NEDGE; }
  float al0 = elog[e*2]   / denom[dN*2];
  float al1 = elog[e*2+1] / denom[dN*2 + 1];
  float xs = x1[sN];
  #pragma unroll
  for (int c = 0; c < 4; ++c) {
    atomicAdd(gat + dN*8 + c,     fmaf(xs, Wl2[c],   bl2[c])  *al0);
    atomicAdd(gat + dN*8 + 4 + c, fmaf(xs, Wl2[4+c], bl2[4+c])*al1);
  }
}

// ---------------------------------------------------------------------------
__global__ void enc_finish(const float* __restrict__ encp, const float* __restrict__ x1,
                           const float* __restrict__ gat2, const float* __restrict__ bias2,
                           const float* __restrict__ l2W, const float* __restrict__ l2b,
                           const float* __restrict__ W1, const float* __restrict__ b1,
                           const float* __restrict__ W2, const float* __restrict__ b2,
                           const float* __restrict__ W3, const float* __restrict__ b3,
                           float* __restrict__ out){
  __shared__ float hb[4][64];
  int wv = threadIdx.x >> 6, lane = threadIdx.x & 63;
  int n = blockIdx.x*4 + wv;
  float x2v = l2b[0];
  #pragma unroll
  for (int c = 0; c < 8; ++c)
    x2v = fmaf(frelu(gat2[n*8+c] + bias2[c]), l2W[c], x2v);
  float hv = encp[n*64 + lane] + x1[n]*W1[9998*64 + lane]
           + x2v*W1[9999*64 + lane] + b1[lane];
  hb[wv][lane] = frelu(hv);
  __syncthreads();
  float t = 0.f;
  if (lane < 32) {
    float a2 = b2[lane];
    #pragma unroll
    for (int k = 0; k < 64; ++k) a2 = fmaf(hb[wv][k], W2[k*32 + lane], a2);
    t = frelu(a2) * W3[lane];
  }
  #pragma unroll
  for (int m = 1; m < 64; m <<= 1) t += __shfl_xor(t, m, 64);
  if (lane == 0) out[n] = t + b3[0];
}

// ---------------------------------------------------------------------------
extern "C" void kernel_launch(void* const* d_in, const int* in_sizes, int n_in,
                              void* d_out, int out_size, void* d_ws, size_t ws_size,
                              hipStream_t stream){
  (void)in_sizes; (void)n_in; (void)out_size; (void)ws_size;
  const float* x    = (const float*)d_in[0];
  const int*   ei   = (const int*)  d_in[1];
  const float* Wl1  = (const float*)d_in[2];
  const float* bl1  = (const float*)d_in[3];
  const float* Wr1  = (const float*)d_in[4];
  const float* br1  = (const float*)d_in[5];
  const float* att1 = (const float*)d_in[6];
  const float* bias1= (const float*)d_in[7];
  const float* l1W  = (const float*)d_in[8];
  const float* l1b  = (const float*)d_in[9];
  const float* Wl2  = (const float*)d_in[10];
  const float* bl2  = (const float*)d_in[11];
  const float* Wr2  = (const float*)d_in[12];
  const float* br2  = (const float*)d_in[13];
  const float* att2 = (const float*)d_in[14];
  const float* bias2= (const float*)d_in[15];
  const float* l2W  = (const float*)d_in[16];
  const float* l2b  = (const float*)d_in[17];
  const float* eW1  = (const float*)d_in[18];
  const float* eb1  = (const float*)d_in[19];
  const float* eW2  = (const float*)d_in[20];
  const float* eb2  = (const float*)d_in[21];
  const float* eW3  = (const float*)d_in[22];
  const float* eb3  = (const float*)d_in[23];

  float* ws = (float*)d_ws;
  size_t off = 0;
  auto alloc = [&](size_t nel){ float* pp = ws + off; off += (nel + 63) & ~size_t(63); return pp; };
  _Float16* Wimg = (_Float16*)alloc((size_t)160*CHWP/2);
  float* elog   = alloc((size_t)(NEDGE+NNODE)*2);
  // contiguous zero block [xl1 .. gat2] = ZN floats:
  float* xl1    = alloc(NNODE*8);
  float* xr1    = alloc(NNODE*8);
  float* encp   = alloc(NNODE*64);
  float* denom1 = alloc(NNODE*2);
  float* gat1   = alloc(NNODE*8);
  float* denom2 = alloc(NNODE*2);
  float* gat2   = alloc(NNODE*8);
  float* x1a    = alloc(NNODE);
  // dead scratch for ablation clones (never read):
  float* sxl    = alloc(NNODE*8);
  float* sxr    = alloc(NNODE*8);
  float* senc   = alloc(NNODE*64);

  const int ET = NEDGE + NNODE;
  const int eb = (ET + 255)/256;

  prep_wt<<<(160*CHWP + 255)/256, 256, 0, stream>>>(Wl1, Wr1, eW1, Wimg, xl1);

  // ---- ablation clones (outputs discarded; per-dispatch dur_us is the data)
  k1_tmpl<14><<<471, 256, 0, stream>>>(x, Wimg, bl1, br1, sxl, sxr, senc); // noW
  k1_tmpl<13><<<471, 256, 0, stream>>>(x, Wimg, bl1, br1, sxl, sxr, senc); // noX
  k1_tmpl<11><<<471, 256, 0, stream>>>(x, Wimg, bl1, br1, sxl, sxr, senc); // noC
  k1_tmpl< 7><<<471, 256, 0, stream>>>(x, Wimg, bl1, br1, sxl, sxr, senc); // noB

  // ---- real pipeline
  k1_tmpl<15><<<471, 256, 0, stream>>>(x, Wimg, bl1, br1, xl1, xr1, encp);

  edgeA1<<<eb, 256, 0, stream>>>(ei, xl1, xr1, att1, elog, denom1);
  edgeB1<<<eb, 256, 0, stream>>>(ei, elog, denom1, xl1, gat1);
  node_x1<<<(NNODE+255)/256, 256, 0, stream>>>(gat1, bias1, l1W, l1b, x1a);

  edgeA2<<<eb, 256, 0, stream>>>(ei, x1a, Wl2, bl2, Wr2, br2, att2, elog, denom2);
  edgeB2<<<eb, 256, 0, stream>>>(ei, elog, denom2, x1a, Wl2, bl2, gat2);

  enc_finish<<<NNODE/4, 256, 0, stream>>>(encp, x1a, gat2, bias2, l2W, l2b,
                                          eW1, eb1, eW2, eb2, eW3, eb3,
                                          (float*)d_out);
}

// Round 14
// 707.328 us; speedup vs baseline: 2.3348x; 2.3348x over previous
//
#include <hip/hip_runtime.h>
#include <math.h>

#define NNODE 10000
#define INCH  9998
#define NEDGE 320000
#define CHW2  10240        // halves per W chunk image: [2][80][64]
#define NSLAB 800000       // floats per K-split slab (10000 rows x 80 cols)
#define ZN2   200064       // floats zeroed: [denom1, gat1, denom2, gat2]

typedef _Float16 half8 __attribute__((ext_vector_type(8)));
typedef float    f32x4 __attribute__((ext_vector_type(4)));

__device__ __forceinline__ float lrelu(float v){ return v > 0.f ? v : 0.2f*v; }
__device__ __forceinline__ float frelu(float v){ return v > 0.f ? v : 0.f; }

// ---------------------------------------------------------------------------
// Weight prep: Wimg[chunk][sp][col][k64], unpadded (16B-aligned half8 reads
// from GLOBAL — no LDS anywhere in k1 now). sp0 = fp16 hi, sp1 = 2048-scaled
// residual; k >= INCH zero-padded. Also zero-inits denom/gat block.
__global__ void prep_wt(const float* __restrict__ Wl, const float* __restrict__ Wr,
                        const float* __restrict__ We, _Float16* __restrict__ Wimg,
                        float* __restrict__ zblk){
  int idx = blockIdx.x*256 + threadIdx.x;
  if (idx < ZN2) zblk[idx] = 0.f;
  if (idx >= 160*CHW2) return;
  int ci  = idx / CHW2;
  int rem = idx - ci*CHW2;
  int sp  = rem / 5120;
  int r2  = rem - sp*5120;
  int col = r2 >> 6;
  int k   = ci*64 + (r2 & 63);
  float v = 0.f;
  if (k < INCH)
    v = (col < 8) ? Wl[k*8 + col] : (col < 16 ? Wr[k*8 + (col-8)] : We[k*64 + (col-16)]);
  _Float16 h = (_Float16)v;
  Wimg[idx] = sp ? (_Float16)((v - (float)h) * 2048.f) : h;
}

// ---------------------------------------------------------------------------
// r14: fully wave-independent 80-col GEMM. 5000 waves (1250 blocks, ZERO LDS,
// no barriers): wave = 16 rows x 80 cols x 1280-K slice. x per-lane in regs
// (r8 pattern); W half8 fragments read DIRECTLY from L2-resident Wimg.
// r13 ablation: W-staging free, cost = stage->drain->compute chain at only
// 2 waves/SIMD. Fix = TLP (16 waves/CU) + no per-chunk drain at all.
// Epilogue: plain stores to 8 K-split slabs (no atomics); reduce80 sums them.
#define TILE(T, S, AH, AL, H, L) { \
  half8 bh = *(const half8*)(wb + (T)*1024 + (S)*32); \
  half8 bl = *(const half8*)(wb + 5120 + (T)*1024 + (S)*32); \
  H = __builtin_amdgcn_mfma_f32_16x16x32_f16(AH, bh, H, 0, 0, 0); \
  L = __builtin_amdgcn_mfma_f32_16x16x32_f16(AH, bl, L, 0, 0, 0); \
  L = __builtin_amdgcn_mfma_f32_16x16x32_f16(AL, bh, L, 0, 0, 0); }

#define KSTEP(S, XA, XB, XC, XD) { \
  _Float16 h0_=(_Float16)XA.x, h1_=(_Float16)XA.y, h2_=(_Float16)XB.x, h3_=(_Float16)XB.y; \
  _Float16 h4_=(_Float16)XC.x, h5_=(_Float16)XC.y, h6_=(_Float16)XD.x, h7_=(_Float16)XD.y; \
  half8 ah = {h0_,h1_,h2_,h3_,h4_,h5_,h6_,h7_}; \
  half8 al = {(_Float16)((XA.x-(float)h0_)*2048.f), (_Float16)((XA.y-(float)h1_)*2048.f), \
              (_Float16)((XB.x-(float)h2_)*2048.f), (_Float16)((XB.y-(float)h3_)*2048.f), \
              (_Float16)((XC.x-(float)h4_)*2048.f), (_Float16)((XC.y-(float)h5_)*2048.f), \
              (_Float16)((XD.x-(float)h6_)*2048.f), (_Float16)((XD.y-(float)h7_)*2048.f)}; \
  TILE(0, S, ah, al, ach0, acl0) \
  TILE(1, S, ah, al, ach1, acl1) \
  TILE(2, S, ah, al, ach2, acl2) \
  TILE(3, S, ah, al, ach3, acl3) \
  TILE(4, S, ah, al, ach4, acl4) }

#define EPI(T, H, L) { \
  size_t base_ = (size_t)ks*NSLAB + (size_t)(rg*16 + 4*g)*80 + 16*(T) + c0; \
  slab[base_      ] = H[0] + L[0]*inv2048; \
  slab[base_ +  80] = H[1] + L[1]*inv2048; \
  slab[base_ + 160] = H[2] + L[2]*inv2048; \
  slab[base_ + 240] = H[3] + L[3]*inv2048; }

__global__ __launch_bounds__(256, 4)
void k1_fused(const float* __restrict__ x, const _Float16* __restrict__ Wimg,
              float* __restrict__ slab){
  const int lane = threadIdx.x & 63;
  const int wv   = threadIdx.x >> 6;
  const int g    = lane >> 4;           // k-group 0..3
  const int c0   = lane & 15;           // MFMA col / A-row index
  const int wg   = blockIdx.x*4 + wv;   // 0..4999
  const int rg   = wg % 625;            // row-group: rows rg*16..+15 (<10000)
  const int ks   = wg / 625;            // K-split 0..7 (block waves share ks)
  const int arow = rg*16 + c0;
  const int xbase= arow*INCH;
  const int maxi = NNODE*INCH - 2;

  f32x4 ach0={0,0,0,0}, ach1={0,0,0,0}, ach2={0,0,0,0}, ach3={0,0,0,0}, ach4={0,0,0,0};
  f32x4 acl0={0,0,0,0}, acl1={0,0,0,0}, acl2={0,0,0,0}, acl3={0,0,0,0}, acl4={0,0,0,0};

  const _Float16* wb0 = Wimg + (size_t)(ks*20)*CHW2 + c0*64 + g*8;

  #pragma unroll 1
  for (int c = 0; c < 20; ++c){
    const int k0 = ks*1280 + c*64;
    const _Float16* wb = wb0 + (size_t)c*CHW2;
    // K-step s=0: lane covers k = k0 + 8g .. +7
    float2 x0 = *(const float2*)(x + min(xbase + k0 + 8*g     , maxi));
    float2 x1 = *(const float2*)(x + min(xbase + k0 + 8*g +  2, maxi));
    float2 x2 = *(const float2*)(x + min(xbase + k0 + 8*g +  4, maxi));
    float2 x3 = *(const float2*)(x + min(xbase + k0 + 8*g +  6, maxi));
    // K-step s=1: k = k0 + 32 + 8g .. +7
    float2 x4 = *(const float2*)(x + min(xbase + k0 + 32 + 8*g     , maxi));
    float2 x5 = *(const float2*)(x + min(xbase + k0 + 32 + 8*g +  2, maxi));
    float2 x6 = *(const float2*)(x + min(xbase + k0 + 32 + 8*g +  4, maxi));
    float2 x7 = *(const float2*)(x + min(xbase + k0 + 32 + 8*g +  6, maxi));
    KSTEP(0, x0, x1, x2, x3)
    KSTEP(1, x4, x5, x6, x7)
  }

  // epilogue: C/D layout col=lane&15, row=4*(lane>>4)+reg [m89-verified];
  // plain stores into this wave's K-split slab (no atomics, no bias here).
  const float inv2048 = 4.8828125e-4f;
  EPI(0, ach0, acl0) EPI(1, ach1, acl1) EPI(2, ach2, acl2)
  EPI(3, ach3, acl3) EPI(4, ach4, acl4)
}

// ---------------------------------------------------------------------------
// Sum the 8 K-split slabs, apply biases, scatter to xl1/xr1/encp layouts.
__global__ void reduce80(const float* __restrict__ slab, const float* __restrict__ bl1,
                         const float* __restrict__ br1, float* __restrict__ xl1,
                         float* __restrict__ xr1, float* __restrict__ encp){
  int f = blockIdx.x*256 + threadIdx.x;
  if (f >= NSLAB) return;
  float s = 0.f;
  #pragma unroll
  for (int k = 0; k < 8; ++k) s += slab[(size_t)k*NSLAB + f];
  int n = f / 80;
  int col = f - n*80;
  if (col < 8)       xl1[n*8 + col]       = s + bl1[col];
  else if (col < 16) xr1[n*8 + col - 8]   = s + br1[col - 8];
  else               encp[n*64 + col - 16] = s;
}

// ---------------------------------------------------------------------------
// conv1 edge pass A: logits -> exp -> store + denom. (No max subtraction:
// logits are O(1); exp safe in fp32; softmax is shift-invariant.)
__global__ void edgeA1(const int* __restrict__ ei, const float* __restrict__ xl,
                       const float* __restrict__ xr, const float* __restrict__ att,
                       float* __restrict__ elog, float* __restrict__ denom){
  int e = blockIdx.x*blockDim.x + threadIdx.x;
  if (e >= NEDGE + NNODE) return;
  int sN, dN;
  if (e < NEDGE) { sN = ei[e]; dN = ei[NEDGE + e]; } else { sN = dN = e - NEDGE; }
  const float4 a0 = *(const float4*)(xl + sN*8);
  const float4 a1 = *(const float4*)(xl + sN*8 + 4);
  const float4 b0 = *(const float4*)(xr + dN*8);
  const float4 b1 = *(const float4*)(xr + dN*8 + 4);
  float l0 = att[0]*lrelu(a0.x+b0.x) + att[1]*lrelu(a0.y+b0.y)
           + att[2]*lrelu(a0.z+b0.z) + att[3]*lrelu(a0.w+b0.w);
  float l1 = att[4]*lrelu(a1.x+b1.x) + att[5]*lrelu(a1.y+b1.y)
           + att[6]*lrelu(a1.z+b1.z) + att[7]*lrelu(a1.w+b1.w);
  float e0 = expf(l0), e1 = expf(l1);
  elog[e*2]   = e0;
  elog[e*2+1] = e1;
  atomicAdd(denom + dN*2,     e0);
  atomicAdd(denom + dN*2 + 1, e1);
}

__global__ void edgeB1(const int* __restrict__ ei, const float* __restrict__ elog,
                       const float* __restrict__ denom, const float* __restrict__ xl,
                       float* __restrict__ gat){
  int e = blockIdx.x*blockDim.x + threadIdx.x;
  if (e >= NEDGE + NNODE) return;
  int sN, dN;
  if (e < NEDGE) { sN = ei[e]; dN = ei[NEDGE + e]; } else { sN = dN = e - NEDGE; }
  float al0 = elog[e*2]   / denom[dN*2];
  float al1 = elog[e*2+1] / denom[dN*2 + 1];
  const float4 a0 = *(const float4*)(xl + sN*8);
  const float4 a1 = *(const float4*)(xl + sN*8 + 4);
  atomicAdd(gat + dN*8 + 0, a0.x*al0);
  atomicAdd(gat + dN*8 + 1, a0.y*al0);
  atomicAdd(gat + dN*8 + 2, a0.z*al0);
  atomicAdd(gat + dN*8 + 3, a0.w*al0);
  atomicAdd(gat + dN*8 + 4, a1.x*al1);
  atomicAdd(gat + dN*8 + 5, a1.y*al1);
  atomicAdd(gat + dN*8 + 6, a1.z*al1);
  atomicAdd(gat + dN*8 + 7, a1.w*al1);
}

// x1 = relu(gat1+bias1)@lin1_W + lin1_b
__global__ void node_x1(const float* __restrict__ gat, const float* __restrict__ bias1,
                        const float* __restrict__ linW, const float* __restrict__ linb,
                        float* __restrict__ x1){
  int n = blockIdx.x*blockDim.x + threadIdx.x;
  if (n >= NNODE) return;
  float sacc = linb[0];
  #pragma unroll
  for (int c = 0; c < 8; ++c)
    sacc = fmaf(frelu(gat[n*8+c] + bias1[c]), linW[c], sacc);
  x1[n] = sacc;
}

// conv2 is rank-1: per-endpoint features recomputed from scalar x1.
__global__ void edgeA2(const int* __restrict__ ei, const float* __restrict__ x1,
                       const float* __restrict__ Wl2, const float* __restrict__ bl2,
                       const float* __restrict__ Wr2, const float* __restrict__ br2,
                       const float* __restrict__ att,
                       float* __restrict__ elog, float* __restrict__ denom){
  int e = blockIdx.x*blockDim.x + threadIdx.x;
  if (e >= NEDGE + NNODE) return;
  int sN, dN;
  if (e < NEDGE) { sN = ei[e]; dN = ei[NEDGE + e]; } else { sN = dN = e - NEDGE; }
  float xs = x1[sN], xd = x1[dN];
  float l0 = 0.f, l1 = 0.f;
  #pragma unroll
  for (int c = 0; c < 4; ++c) {
    l0 = fmaf(att[c],   lrelu(fmaf(xs, Wl2[c],   bl2[c])   + fmaf(xd, Wr2[c],   br2[c])),   l0);
    l1 = fmaf(att[4+c], lrelu(fmaf(xs, Wl2[4+c], bl2[4+c]) + fmaf(xd, Wr2[4+c], br2[4+c])), l1);
  }
  float e0 = expf(l0), e1 = expf(l1);
  elog[e*2]   = e0;
  elog[e*2+1] = e1;
  atomicAdd(denom + dN*2,     e0);
  atomicAdd(denom + dN*2 + 1, e1);
}

__global__ void edgeB2(const int* __restrict__ ei, const float* __restrict__ elog,
                       const float* __restrict__ denom, const float* __restrict__ x1,
                       const float* __restrict__ Wl2, const float* __restrict__ bl2,
                       float* __restrict__ gat){
  int e = blockIdx.x*blockDim.x + threadIdx.x;
  if (e >= NEDGE + NNODE) return;
  int sN, dN;
  if (e < NEDGE) { sN = ei[e]; dN = ei[NEDGE + e]; } else { sN = dN = e - NEDGE; }
  float al0 = elog[e*2]   / denom[dN*2];
  float al1 = elog[e*2+1] / denom[dN*2 + 1];
  float xs = x1[sN];
  #pragma unroll
  for (int c = 0; c < 4; ++c) {
    atomicAdd(gat + dN*8 + c,     fmaf(xs, Wl2[c],   bl2[c])  *al0);
    atomicAdd(gat + dN*8 + 4 + c, fmaf(xs, Wl2[4+c], bl2[4+c])*al1);
  }
}

// ---------------------------------------------------------------------------
// x2 inline; h1 = relu(encp + x1*W1[9998] + x2*W1[9999] + b1);
// h2 = relu(h1@W2+b2); out = h2@W3 + b3.  One node per wave.
__global__ void enc_finish(const float* __restrict__ encp, const float* __restrict__ x1,
                           const float* __restrict__ gat2, const float* __restrict__ bias2,
                           const float* __restrict__ l2W, const float* __restrict__ l2b,
                           const float* __restrict__ W1, const float* __restrict__ b1,
                           const float* __restrict__ W2, const float* __restrict__ b2,
                           const float* __restrict__ W3, const float* __restrict__ b3,
                           float* __restrict__ out){
  __shared__ float hb[4][64];
  int wv = threadIdx.x >> 6, lane = threadIdx.x & 63;
  int n = blockIdx.x*4 + wv;
  float x2v = l2b[0];
  #pragma unroll
  for (int c = 0; c < 8; ++c)
    x2v = fmaf(frelu(gat2[n*8+c] + bias2[c]), l2W[c], x2v);
  float hv = encp[n*64 + lane] + x1[n]*W1[9998*64 + lane]
           + x2v*W1[9999*64 + lane] + b1[lane];
  hb[wv][lane] = frelu(hv);
  __syncthreads();
  float t = 0.f;
  if (lane < 32) {
    float a2 = b2[lane];
    #pragma unroll
    for (int k = 0; k < 64; ++k) a2 = fmaf(hb[wv][k], W2[k*32 + lane], a2);
    t = frelu(a2) * W3[lane];
  }
  #pragma unroll
  for (int m = 1; m < 64; m <<= 1) t += __shfl_xor(t, m, 64);
  if (lane == 0) out[n] = t + b3[0];
}

// ---------------------------------------------------------------------------
extern "C" void kernel_launch(void* const* d_in, const int* in_sizes, int n_in,
                              void* d_out, int out_size, void* d_ws, size_t ws_size,
                              hipStream_t stream){
  (void)in_sizes; (void)n_in; (void)out_size; (void)ws_size;
  const float* x    = (const float*)d_in[0];
  const int*   ei   = (const int*)  d_in[1];
  const float* Wl1  = (const float*)d_in[2];
  const float* bl1  = (const float*)d_in[3];
  const float* Wr1  = (const float*)d_in[4];
  const float* br1  = (const float*)d_in[5];
  const float* att1 = (const float*)d_in[6];
  const float* bias1= (const float*)d_in[7];
  const float* l1W  = (const float*)d_in[8];
  const float* l1b  = (const float*)d_in[9];
  const float* Wl2  = (const float*)d_in[10];
  const float* bl2  = (const float*)d_in[11];
  const float* Wr2  = (const float*)d_in[12];
  const float* br2  = (const float*)d_in[13];
  const float* att2 = (const float*)d_in[14];
  const float* bias2= (const float*)d_in[15];
  const float* l2W  = (const float*)d_in[16];
  const float* l2b  = (const float*)d_in[17];
  const float* eW1  = (const float*)d_in[18];
  const float* eb1  = (const float*)d_in[19];
  const float* eW2  = (const float*)d_in[20];
  const float* eb2  = (const float*)d_in[21];
  const float* eW3  = (const float*)d_in[22];
  const float* eb3  = (const float*)d_in[23];

  float* ws = (float*)d_ws;
  size_t off = 0;
  auto alloc = [&](size_t nel){ float* pp = ws + off; off += (nel + 63) & ~size_t(63); return pp; };
  _Float16* Wimg = (_Float16*)alloc((size_t)160*CHW2/2);
  float* slab   = alloc((size_t)8*NSLAB);
  float* elog   = alloc((size_t)(NEDGE+NNODE)*2);
  float* xl1    = alloc(NNODE*8);
  float* xr1    = alloc(NNODE*8);
  float* encp   = alloc(NNODE*64);
  // contiguous zero block [denom1 .. gat2] = ZN2 floats:
  float* denom1 = alloc(NNODE*2);
  float* gat1   = alloc(NNODE*8);
  float* denom2 = alloc(NNODE*2);
  float* gat2   = alloc(NNODE*8);
  float* x1a    = alloc(NNODE);

  const int ET = NEDGE + NNODE;
  const int eb = (ET + 255)/256;

  prep_wt<<<(160*CHW2 + 255)/256, 256, 0, stream>>>(Wl1, Wr1, eW1, Wimg, denom1);

  k1_fused<<<1250, 256, 0, stream>>>(x, Wimg, slab);
  reduce80<<<(NSLAB + 255)/256, 256, 0, stream>>>(slab, bl1, br1, xl1, xr1, encp);

  edgeA1<<<eb, 256, 0, stream>>>(ei, xl1, xr1, att1, elog, denom1);
  edgeB1<<<eb, 256, 0, stream>>>(ei, elog, denom1, xl1, gat1);
  node_x1<<<(NNODE+255)/256, 256, 0, stream>>>(gat1, bias1, l1W, l1b, x1a);

  edgeA2<<<eb, 256, 0, stream>>>(ei, x1a, Wl2, bl2, Wr2, br2, att2, elog, denom2);
  edgeB2<<<eb, 256, 0, stream>>>(ei, elog, denom2, x1a, Wl2, bl2, gat2);

  enc_finish<<<NNODE/4, 256, 0, stream>>>(encp, x1a, gat2, bias2, l2W, l2b,
                                          eW1, eb1, eW2, eb2, eW3, eb3,
                                          (float*)d_out);
}

// Round 15
// 509.957 us; speedup vs baseline: 3.2385x; 1.3870x over previous
//
#include <hip/hip_runtime.h>
#include <math.h>

#define NNODE 10000
#define INCH  9998
#define NEDGE 320000
#define KSL   40           // K-slices of 256 (ks 0..39); block does ks=j, j+20
#define WCOL  264          // padded k-stride of W LDS/global slice (halves)
#define WSLH  21120        // halves per W slice: 80*264 (42240 B)
#define NSLAB 800000       // values per output slab (10000 x 80)
#define ZN2   200064       // floats zeroed: [denom1, gat1, denom2, gat2]

typedef _Float16 half8 __attribute__((ext_vector_type(8)));
typedef float    f32x4 __attribute__((ext_vector_type(4)));

__device__ __forceinline__ float lrelu(float v){ return v > 0.f ? v : 0.2f*v; }
__device__ __forceinline__ float frelu(float v){ return v > 0.f ? v : 0.f; }

// ---------------------------------------------------------------------------
// Weight prep: Wpad[ks][col][kk] fp16 (hi only — fp16 W rounding contributes
// ~2.4e-4 output error vs 2.4e-2 threshold; the old hi/lo split was overkill).
// kk >= 256 pad and k >= INCH are zero. Also zero-inits denom/gat block.
__global__ void prep_wt(const float* __restrict__ Wl, const float* __restrict__ Wr,
                        const float* __restrict__ We, _Float16* __restrict__ Wpad,
                        float* __restrict__ zblk){
  int idx = blockIdx.x*256 + threadIdx.x;
  if (idx < ZN2) zblk[idx] = 0.f;
  if (idx >= KSL*WSLH) return;
  int ks  = idx / WSLH;
  int rem = idx - ks*WSLH;
  int col = rem / WCOL;
  int kk  = rem - col*WCOL;
  int k   = ks*256 + kk;
  float v = 0.f;
  if (kk < 256 && k < INCH)
    v = (col < 8) ? Wl[k*8 + col] : (col < 16 ? Wr[k*8 + (col-8)] : We[k*64 + (col-16)]);
  Wpad[idx] = (_Float16)v;
}

// ---------------------------------------------------------------------------
// r15: W LDS-RESIDENT 80-col GEMM (fp16 x fp16 -> fp32 MFMA).
// Diagnosis from r7-r14: wall = per-CU cache-line request throughput; every
// prior variant issued ~16-line VMEM instructions for BOTH x and W. Fix: W
// lives in LDS for a whole 256-K phase (ds_read = no VMEM line traffic, no
// per-chunk staging, no main-loop barriers); only x touches the VMEM path.
// Block (rb, j): 64 rows x 80 cols, accumulates ks = j and j+20 (K=512 total)
// into one acc -> 20 fp16 slabs. 3 blocks/CU (42.2 KB LDS), 12 waves/CU.
#define XL(C, X0, X1, X2, X3) { \
  int kb_ = k0b + (C)*32 + 8*g; \
  X0 = *(const float2*)(x + min(xbase + kb_    , maxi)); \
  X1 = *(const float2*)(x + min(xbase + kb_ + 2, maxi)); \
  X2 = *(const float2*)(x + min(xbase + kb_ + 4, maxi)); \
  X3 = *(const float2*)(x + min(xbase + kb_ + 6, maxi)); }

#define CMP(C, X0, X1, X2, X3) { \
  half8 ah = {(_Float16)X0.x, (_Float16)X0.y, (_Float16)X1.x, (_Float16)X1.y, \
              (_Float16)X2.x, (_Float16)X2.y, (_Float16)X3.x, (_Float16)X3.y}; \
  const _Float16* wp_ = lw + (C)*32 + 8*g; \
  half8 b0 = *(const half8*)(wp_ + (c0     )*WCOL); \
  half8 b1 = *(const half8*)(wp_ + (c0 + 16)*WCOL); \
  half8 b2 = *(const half8*)(wp_ + (c0 + 32)*WCOL); \
  half8 b3 = *(const half8*)(wp_ + (c0 + 48)*WCOL); \
  half8 b4 = *(const half8*)(wp_ + (c0 + 64)*WCOL); \
  a0 = __builtin_amdgcn_mfma_f32_16x16x32_f16(ah, b0, a0, 0, 0, 0); \
  a1 = __builtin_amdgcn_mfma_f32_16x16x32_f16(ah, b1, a1, 0, 0, 0); \
  a2 = __builtin_amdgcn_mfma_f32_16x16x32_f16(ah, b2, a2, 0, 0, 0); \
  a3 = __builtin_amdgcn_mfma_f32_16x16x32_f16(ah, b3, a3, 0, 0, 0); \
  a4 = __builtin_amdgcn_mfma_f32_16x16x32_f16(ah, b4, a4, 0, 0, 0); }

__global__ __launch_bounds__(256, 3)
void k1_fused(const float* __restrict__ x, const _Float16* __restrict__ Wpad,
              _Float16* __restrict__ slabh){
  __shared__ _Float16 lw[WSLH];         // 42240 B — resident W slice
  const int tid  = threadIdx.x;
  const int lane = tid & 63;
  const int wv   = tid >> 6;            // 0..3
  const int g    = lane >> 4;           // k-group 0..3
  const int c0   = lane & 15;
  const int bid  = blockIdx.x;          // 0..3139
  const int j    = bid / 157;           // output slab 0..19
  const int rb   = bid - j*157;         // row block 0..156
  const int arow = rb*64 + wv*16 + c0;
  const int xbase= (arow < NNODE ? arow : NNODE-1)*INCH;
  const int maxi = NNODE*INCH - 2;

  f32x4 a0={0,0,0,0}, a1={0,0,0,0}, a2={0,0,0,0}, a3={0,0,0,0}, a4={0,0,0,0};

  for (int h = 0; h < 2; ++h){
    const int ks  = j + 20*h;
    const int k0b = ks << 8;
    if (h) __syncthreads();             // all waves done reading prev W slice
    {                                    // load W slice (2640 x 16B, coalesced)
      const uint4* src = (const uint4*)(Wpad + (size_t)ks*WSLH);
      uint4* dst = (uint4*)lw;
      #pragma unroll
      for (int i = 0; i < 11; ++i){
        int idx = tid + 256*i;
        if (idx < 2640) dst[idx] = src[idx];
      }
    }
    __syncthreads();                    // W slice visible; main loop barrier-free

    float2 xa0,xa1,xa2,xa3, xb0,xb1,xb2,xb3;
    XL(0, xa0,xa1,xa2,xa3)
    #pragma unroll
    for (int c = 0; c < 8; c += 2){     // 2-slot static pipeline (no reg moves)
      XL(c+1, xb0,xb1,xb2,xb3)
      CMP(c,   xa0,xa1,xa2,xa3)
      if (c + 2 < 8) XL(c+2, xa0,xa1,xa2,xa3)
      CMP(c+1, xb0,xb1,xb2,xb3)
    }
  }

  // epilogue: C/D layout col=lane&15, row=4*(lane>>4)+reg [m89-verified];
  // fp16 slab stores (partial sums sigma~0.2, fp16 err ~4e-5 — negligible).
  const int nodeb = rb*64 + wv*16 + 4*g;
  #define EPI(T, A) { \
    _Pragma("unroll") \
    for (int r = 0; r < 4; ++r){ \
      int row = nodeb + r; \
      if (row < NNODE) \
        slabh[(size_t)j*NSLAB + (size_t)row*80 + 16*(T) + c0] = (_Float16)A[r]; \
    } }
  EPI(0, a0) EPI(1, a1) EPI(2, a2) EPI(3, a3) EPI(4, a4)
}

// ---------------------------------------------------------------------------
// Sum the 20 fp16 slabs, apply biases, scatter to xl1/xr1/encp layouts.
__global__ void reduce80(const _Float16* __restrict__ slabh, const float* __restrict__ bl1,
                         const float* __restrict__ br1, float* __restrict__ xl1,
                         float* __restrict__ xr1, float* __restrict__ encp){
  int f = blockIdx.x*256 + threadIdx.x;
  if (f >= NSLAB) return;
  float s = 0.f;
  #pragma unroll
  for (int k = 0; k < 20; ++k) s += (float)slabh[(size_t)k*NSLAB + f];
  int n = f / 80;
  int col = f - n*80;
  if (col < 8)       xl1[n*8 + col]        = s + bl1[col];
  else if (col < 16) xr1[n*8 + col - 8]    = s + br1[col - 8];
  else               encp[n*64 + col - 16] = s;
}

// ---------------------------------------------------------------------------
// conv1 edge pass A: logits -> exp -> store + denom. (No max subtraction:
// logits are O(1); exp safe in fp32; softmax is shift-invariant.)
__global__ void edgeA1(const int* __restrict__ ei, const float* __restrict__ xl,
                       const float* __restrict__ xr, const float* __restrict__ att,
                       float* __restrict__ elog, float* __restrict__ denom){
  int e = blockIdx.x*blockDim.x + threadIdx.x;
  if (e >= NEDGE + NNODE) return;
  int sN, dN;
  if (e < NEDGE) { sN = ei[e]; dN = ei[NEDGE + e]; } else { sN = dN = e - NEDGE; }
  const float4 a0 = *(const float4*)(xl + sN*8);
  const float4 a1 = *(const float4*)(xl + sN*8 + 4);
  const float4 b0 = *(const float4*)(xr + dN*8);
  const float4 b1 = *(const float4*)(xr + dN*8 + 4);
  float l0 = att[0]*lrelu(a0.x+b0.x) + att[1]*lrelu(a0.y+b0.y)
           + att[2]*lrelu(a0.z+b0.z) + att[3]*lrelu(a0.w+b0.w);
  float l1 = att[4]*lrelu(a1.x+b1.x) + att[5]*lrelu(a1.y+b1.y)
           + att[6]*lrelu(a1.z+b1.z) + att[7]*lrelu(a1.w+b1.w);
  float e0 = expf(l0), e1 = expf(l1);
  elog[e*2]   = e0;
  elog[e*2+1] = e1;
  atomicAdd(denom + dN*2,     e0);
  atomicAdd(denom + dN*2 + 1, e1);
}

__global__ void edgeB1(const int* __restrict__ ei, const float* __restrict__ elog,
                       const float* __restrict__ denom, const float* __restrict__ xl,
                       float* __restrict__ gat){
  int e = blockIdx.x*blockDim.x + threadIdx.x;
  if (e >= NEDGE + NNODE) return;
  int sN, dN;
  if (e < NEDGE) { sN = ei[e]; dN = ei[NEDGE + e]; } else { sN = dN = e - NEDGE; }
  float al0 = elog[e*2]   / denom[dN*2];
  float al1 = elog[e*2+1] / denom[dN*2 + 1];
  const float4 a0 = *(const float4*)(xl + sN*8);
  const float4 a1 = *(const float4*)(xl + sN*8 + 4);
  atomicAdd(gat + dN*8 + 0, a0.x*al0);
  atomicAdd(gat + dN*8 + 1, a0.y*al0);
  atomicAdd(gat + dN*8 + 2, a0.z*al0);
  atomicAdd(gat + dN*8 + 3, a0.w*al0);
  atomicAdd(gat + dN*8 + 4, a1.x*al1);
  atomicAdd(gat + dN*8 + 5, a1.y*al1);
  atomicAdd(gat + dN*8 + 6, a1.z*al1);
  atomicAdd(gat + dN*8 + 7, a1.w*al1);
}

// x1 = relu(gat1+bias1)@lin1_W + lin1_b
__global__ void node_x1(const float* __restrict__ gat, const float* __restrict__ bias1,
                        const float* __restrict__ linW, const float* __restrict__ linb,
                        float* __restrict__ x1){
  int n = blockIdx.x*blockDim.x + threadIdx.x;
  if (n >= NNODE) return;
  float sacc = linb[0];
  #pragma unroll
  for (int c = 0; c < 8; ++c)
    sacc = fmaf(frelu(gat[n*8+c] + bias1[c]), linW[c], sacc);
  x1[n] = sacc;
}

// conv2 is rank-1: per-endpoint features recomputed from scalar x1.
__global__ void edgeA2(const int* __restrict__ ei, const float* __restrict__ x1,
                       const float* __restrict__ Wl2, const float* __restrict__ bl2,
                       const float* __restrict__ Wr2, const float* __restrict__ br2,
                       const float* __restrict__ att,
                       float* __restrict__ elog, float* __restrict__ denom){
  int e = blockIdx.x*blockDim.x + threadIdx.x;
  if (e >= NEDGE + NNODE) return;
  int sN, dN;
  if (e < NEDGE) { sN = ei[e]; dN = ei[NEDGE + e]; } else { sN = dN = e - NEDGE; }
  float xs = x1[sN], xd = x1[dN];
  float l0 = 0.f, l1 = 0.f;
  #pragma unroll
  for (int c = 0; c < 4; ++c) {
    l0 = fmaf(att[c],   lrelu(fmaf(xs, Wl2[c],   bl2[c])   + fmaf(xd, Wr2[c],   br2[c])),   l0);
    l1 = fmaf(att[4+c], lrelu(fmaf(xs, Wl2[4+c], bl2[4+c]) + fmaf(xd, Wr2[4+c], br2[4+c])), l1);
  }
  float e0 = expf(l0), e1 = expf(l1);
  elog[e*2]   = e0;
  elog[e*2+1] = e1;
  atomicAdd(denom + dN*2,     e0);
  atomicAdd(denom + dN*2 + 1, e1);
}

__global__ void edgeB2(const int* __restrict__ ei, const float* __restrict__ elog,
                       const float* __restrict__ denom, const float* __restrict__ x1,
                       const float* __restrict__ Wl2, const float* __restrict__ bl2,
                       float* __restrict__ gat){
  int e = blockIdx.x*blockDim.x + threadIdx.x;
  if (e >= NEDGE + NNODE) return;
  int sN, dN;
  if (e < NEDGE) { sN = ei[e]; dN = ei[NEDGE + e]; } else { sN = dN = e - NEDGE; }
  float al0 = elog[e*2]   / denom[dN*2];
  float al1 = elog[e*2+1] / denom[dN*2 + 1];
  float xs = x1[sN];
  #pragma unroll
  for (int c = 0; c < 4; ++c) {
    atomicAdd(gat + dN*8 + c,     fmaf(xs, Wl2[c],   bl2[c])  *al0);
    atomicAdd(gat + dN*8 + 4 + c, fmaf(xs, Wl2[4+c], bl2[4+c])*al1);
  }
}

// ---------------------------------------------------------------------------
// x2 inline; h1 = relu(encp + x1*W1[9998] + x2*W1[9999] + b1);
// h2 = relu(h1@W2+b2); out = h2@W3 + b3.  One node per wave.
__global__ void enc_finish(const float* __restrict__ encp, const float* __restrict__ x1,
                           const float* __restrict__ gat2, const float* __restrict__ bias2,
                           const float* __restrict__ l2W, const float* __restrict__ l2b,
                           const float* __restrict__ W1, const float* __restrict__ b1,
                           const float* __restrict__ W2, const float* __restrict__ b2,
                           const float* __restrict__ W3, const float* __restrict__ b3,
                           float* __restrict__ out){
  __shared__ float hb[4][64];
  int wv = threadIdx.x >> 6, lane = threadIdx.x & 63;
  int n = blockIdx.x*4 + wv;
  float x2v = l2b[0];
  #pragma unroll
  for (int c = 0; c < 8; ++c)
    x2v = fmaf(frelu(gat2[n*8+c] + bias2[c]), l2W[c], x2v);
  float hv = encp[n*64 + lane] + x1[n]*W1[9998*64 + lane]
           + x2v*W1[9999*64 + lane] + b1[lane];
  hb[wv][lane] = frelu(hv);
  __syncthreads();
  float t = 0.f;
  if (lane < 32) {
    float a2 = b2[lane];
    #pragma unroll
    for (int k = 0; k < 64; ++k) a2 = fmaf(hb[wv][k], W2[k*32 + lane], a2);
    t = frelu(a2) * W3[lane];
  }
  #pragma unroll
  for (int m = 1; m < 64; m <<= 1) t += __shfl_xor(t, m, 64);
  if (lane == 0) out[n] = t + b3[0];
}

// ---------------------------------------------------------------------------
extern "C" void kernel_launch(void* const* d_in, const int* in_sizes, int n_in,
                              void* d_out, int out_size, void* d_ws, size_t ws_size,
                              hipStream_t stream){
  (void)in_sizes; (void)n_in; (void)out_size; (void)ws_size;
  const float* x    = (const float*)d_in[0];
  const int*   ei   = (const int*)  d_in[1];
  const float* Wl1  = (const float*)d_in[2];
  const float* bl1  = (const float*)d_in[3];
  const float* Wr1  = (const float*)d_in[4];
  const float* br1  = (const float*)d_in[5];
  const float* att1 = (const float*)d_in[6];
  const float* bias1= (const float*)d_in[7];
  const float* l1W  = (const float*)d_in[8];
  const float* l1b  = (const float*)d_in[9];
  const float* Wl2  = (const float*)d_in[10];
  const float* bl2  = (const float*)d_in[11];
  const float* Wr2  = (const float*)d_in[12];
  const float* br2  = (const float*)d_in[13];
  const float* att2 = (const float*)d_in[14];
  const float* bias2= (const float*)d_in[15];
  const float* l2W  = (const float*)d_in[16];
  const float* l2b  = (const float*)d_in[17];
  const float* eW1  = (const float*)d_in[18];
  const float* eb1  = (const float*)d_in[19];
  const float* eW2  = (const float*)d_in[20];
  const float* eb2  = (const float*)d_in[21];
  const float* eW3  = (const float*)d_in[22];
  const float* eb3  = (const float*)d_in[23];

  float* ws = (float*)d_ws;
  size_t off = 0;
  auto alloc = [&](size_t nel){ float* pp = ws + off; off += (nel + 63) & ~size_t(63); return pp; };
  _Float16* Wpad  = (_Float16*)alloc((size_t)KSL*WSLH/2);
  _Float16* slabh = (_Float16*)alloc((size_t)20*NSLAB/2);   // 32 MB
  float* elog   = alloc((size_t)(NEDGE+NNODE)*2);
  float* xl1    = alloc(NNODE*8);
  float* xr1    = alloc(NNODE*8);
  float* encp   = alloc(NNODE*64);
  // contiguous zero block [denom1 .. gat2] = ZN2 floats:
  float* denom1 = alloc(NNODE*2);
  float* gat1   = alloc(NNODE*8);
  float* denom2 = alloc(NNODE*2);
  float* gat2   = alloc(NNODE*8);
  float* x1a    = alloc(NNODE);

  const int ET = NEDGE + NNODE;
  const int eb = (ET + 255)/256;

  prep_wt<<<(KSL*WSLH + 255)/256, 256, 0, stream>>>(Wl1, Wr1, eW1, Wpad, denom1);

  k1_fused<<<157*20, 256, 0, stream>>>(x, Wpad, slabh);
  reduce80<<<(NSLAB + 255)/256, 256, 0, stream>>>(slabh, bl1, br1, xl1, xr1, encp);

  edgeA1<<<eb, 256, 0, stream>>>(ei, xl1, xr1, att1, elog, denom1);
  edgeB1<<<eb, 256, 0, stream>>>(ei, elog, denom1, xl1, gat1);
  node_x1<<<(NNODE+255)/256, 256, 0, stream>>>(gat1, bias1, l1W, l1b, x1a);

  edgeA2<<<eb, 256, 0, stream>>>(ei, x1a, Wl2, bl2, Wr2, br2, att2, elog, denom2);
  edgeB2<<<eb, 256, 0, stream>>>(ei, elog, denom2, x1a, Wl2, bl2, gat2);

  enc_finish<<<NNODE/4, 256, 0, stream>>>(encp, x1a, gat2, bias2, l2W, l2b,
                                          eW1, eb1, eW2, eb2, eW3, eb3,
                                          (float*)d_out);
}

// Round 16
// 219.722 us; speedup vs baseline: 7.5162x; 2.3209x over previous
//
#include <hip/hip_runtime.h>
#include <math.h>

#define NNODE 10000
#define INCH  9998
#define NEDGE 320000
#define KSL   40           // K-slices of 256 (ks 0..39); k1 block does ks=j, j+20
#define WCOL  264          // padded k-stride of W slice (halves)
#define WSLH  21120        // halves per W slice: 80*264 (42240 B)
#define NSLAB 800000       // values per output slab (10000 x 80)
#define ZNI   20096        // ints zeroed: [deg(10048), cnt(10048)]

typedef _Float16 half8 __attribute__((ext_vector_type(8)));
typedef float    f32x4 __attribute__((ext_vector_type(4)));

__device__ __forceinline__ float lrelu(float v){ return v > 0.f ? v : 0.2f*v; }
__device__ __forceinline__ float frelu(float v){ return v > 0.f ? v : 0.f; }

#define RED1(v) { _Pragma("unroll") for (int m_ = 1; m_ < 64; m_ <<= 1) v += __shfl_xor(v, m_, 64); }

// ---------------------------------------------------------------------------
// Weight prep (unchanged r15 math): Wpad[ks][col][kk] fp16. Also zero-inits
// the CSR counter block (deg, cnt — ints, re-zeroed every launch for replays).
__global__ void prep_wt(const float* __restrict__ Wl, const float* __restrict__ Wr,
                        const float* __restrict__ We, _Float16* __restrict__ Wpad,
                        int* __restrict__ zint){
  int idx = blockIdx.x*256 + threadIdx.x;
  if (idx < ZNI) zint[idx] = 0;
  if (idx >= KSL*WSLH) return;
  int ks  = idx / WSLH;
  int rem = idx - ks*WSLH;
  int col = rem / WCOL;
  int kk  = rem - col*WCOL;
  int k   = ks*256 + kk;
  float v = 0.f;
  if (kk < 256 && k < INCH)
    v = (col < 8) ? Wl[k*8 + col] : (col < 16 ? Wr[k*8 + (col-8)] : We[k*64 + (col-16)]);
  Wpad[idx] = (_Float16)v;
}

// ---------------------------------------------------------------------------
// k1 (r15, PROVEN: broke the line-throughput wall): W LDS-resident fp16 GEMM.
#define XL(C, X0, X1, X2, X3) { \
  int kb_ = k0b + (C)*32 + 8*g; \
  X0 = *(const float2*)(x + min(xbase + kb_    , maxi)); \
  X1 = *(const float2*)(x + min(xbase + kb_ + 2, maxi)); \
  X2 = *(const float2*)(x + min(xbase + kb_ + 4, maxi)); \
  X3 = *(const float2*)(x + min(xbase + kb_ + 6, maxi)); }

#define CMP(C, X0, X1, X2, X3) { \
  half8 ah = {(_Float16)X0.x, (_Float16)X0.y, (_Float16)X1.x, (_Float16)X1.y, \
              (_Float16)X2.x, (_Float16)X2.y, (_Float16)X3.x, (_Float16)X3.y}; \
  const _Float16* wp_ = lw + (C)*32 + 8*g; \
  half8 b0 = *(const half8*)(wp_ + (c0     )*WCOL); \
  half8 b1 = *(const half8*)(wp_ + (c0 + 16)*WCOL); \
  half8 b2 = *(const half8*)(wp_ + (c0 + 32)*WCOL); \
  half8 b3 = *(const half8*)(wp_ + (c0 + 48)*WCOL); \
  half8 b4 = *(const half8*)(wp_ + (c0 + 64)*WCOL); \
  a0 = __builtin_amdgcn_mfma_f32_16x16x32_f16(ah, b0, a0, 0, 0, 0); \
  a1 = __builtin_amdgcn_mfma_f32_16x16x32_f16(ah, b1, a1, 0, 0, 0); \
  a2 = __builtin_amdgcn_mfma_f32_16x16x32_f16(ah, b2, a2, 0, 0, 0); \
  a3 = __builtin_amdgcn_mfma_f32_16x16x32_f16(ah, b3, a3, 0, 0, 0); \
  a4 = __builtin_amdgcn_mfma_f32_16x16x32_f16(ah, b4, a4, 0, 0, 0); }

__global__ __launch_bounds__(256, 3)
void k1_fused(const float* __restrict__ x, const _Float16* __restrict__ Wpad,
              _Float16* __restrict__ slabh){
  __shared__ _Float16 lw[WSLH];
  const int tid  = threadIdx.x;
  const int lane = tid & 63;
  const int wv   = tid >> 6;
  const int g    = lane >> 4;
  const int c0   = lane & 15;
  const int bid  = blockIdx.x;
  const int j    = bid / 157;           // output slab 0..19
  const int rb   = bid - j*157;         // row block 0..156
  const int arow = rb*64 + wv*16 + c0;
  const int xbase= (arow < NNODE ? arow : NNODE-1)*INCH;
  const int maxi = NNODE*INCH - 2;

  f32x4 a0={0,0,0,0}, a1={0,0,0,0}, a2={0,0,0,0}, a3={0,0,0,0}, a4={0,0,0,0};

  for (int h = 0; h < 2; ++h){
    const int ks  = j + 20*h;
    const int k0b = ks << 8;
    if (h) __syncthreads();
    {
      const uint4* src = (const uint4*)(Wpad + (size_t)ks*WSLH);
      uint4* dst = (uint4*)lw;
      #pragma unroll
      for (int i = 0; i < 11; ++i){
        int idx = tid + 256*i;
        if (idx < 2640) dst[idx] = src[idx];
      }
    }
    __syncthreads();

    float2 xa0,xa1,xa2,xa3, xb0,xb1,xb2,xb3;
    XL(0, xa0,xa1,xa2,xa3)
    #pragma unroll
    for (int c = 0; c < 8; c += 2){
      XL(c+1, xb0,xb1,xb2,xb3)
      CMP(c,   xa0,xa1,xa2,xa3)
      if (c + 2 < 8) XL(c+2, xa0,xa1,xa2,xa3)
      CMP(c+1, xb0,xb1,xb2,xb3)
    }
  }

  const int nodeb = rb*64 + wv*16 + 4*g;
  #define EPI(T, A) { \
    _Pragma("unroll") \
    for (int r = 0; r < 4; ++r){ \
      int row = nodeb + r; \
      if (row < NNODE) \
        slabh[(size_t)j*NSLAB + (size_t)row*80 + 16*(T) + c0] = (_Float16)A[r]; \
    } }
  EPI(0, a0) EPI(1, a1) EPI(2, a2) EPI(3, a3) EPI(4, a4)
}

// ---------------------------------------------------------------------------
__global__ void reduce80(const _Float16* __restrict__ slabh, const float* __restrict__ bl1,
                         const float* __restrict__ br1, float* __restrict__ xl1,
                         float* __restrict__ xr1, float* __restrict__ encp){
  int f = blockIdx.x*256 + threadIdx.x;
  if (f >= NSLAB) return;
  float s = 0.f;
  #pragma unroll
  for (int k = 0; k < 20; ++k) s += (float)slabh[(size_t)k*NSLAB + f];
  int n = f / 80;
  int col = f - n*80;
  if (col < 8)       xl1[n*8 + col]        = s + bl1[col];
  else if (col < 16) xr1[n*8 + col - 8]    = s + br1[col - 8];
  else               encp[n*64 + col - 16] = s;
}

// ---------------------------------------------------------------------------
// CSR build (dst-grouped edge list incl. self-loops). deg/cnt pre-zeroed.
__global__ void csr_hist(const int* __restrict__ ei, int* __restrict__ deg){
  int e = blockIdx.x*256 + threadIdx.x;
  if (e >= NEDGE + NNODE) return;
  int d = (e < NEDGE) ? ei[NEDGE + e] : e - NEDGE;
  atomicAdd(deg + d, 1);
}

// single-block exclusive scan (256 thr x 40-elem serial segments + LDS scan)
__global__ void csr_scan(const int* __restrict__ deg, int* __restrict__ offs){
  __shared__ int ssum[256];
  int t = threadIdx.x;
  int base = t*40;
  int s = 0;
  for (int i = 0; i < 40; ++i){
    int idx = base + i;
    s += (idx < NNODE) ? deg[idx] : 0;
  }
  ssum[t] = s;
  __syncthreads();
  for (int d = 1; d < 256; d <<= 1){
    int v = (t >= d) ? ssum[t - d] : 0;
    __syncthreads();
    ssum[t] += v;
    __syncthreads();
  }
  int run = (t == 0) ? 0 : ssum[t - 1];
  for (int i = 0; i < 40; ++i){
    int idx = base + i;
    if (idx < NNODE){ offs[idx] = run; run += deg[idx]; }
  }
}

__global__ void csr_scat(const int* __restrict__ ei, const int* __restrict__ offs,
                         int* __restrict__ cnt, int* __restrict__ csrc){
  int e = blockIdx.x*256 + threadIdx.x;
  if (e >= NEDGE + NNODE) return;
  int s, d;
  if (e < NEDGE){ s = ei[e]; d = ei[NEDGE + e]; } else { s = d = e - NEDGE; }
  int p = offs[d] + atomicAdd(cnt + d, 1);
  csrc[p] = s;
}

// ---------------------------------------------------------------------------
// conv1 aggregation, wave-per-dst, ONE pass, NO atomics:
// gat[c] = (SUM_e e*xl[s][c]) / (SUM_e e); x1 computed in-register.
__global__ __launch_bounds__(256)
void conv1_agg(const int* __restrict__ offs, const int* __restrict__ deg,
               const int* __restrict__ csrc, const float* __restrict__ xl1,
               const float* __restrict__ xr1, const float* __restrict__ att,
               const float* __restrict__ bias1, const float* __restrict__ linW,
               const float* __restrict__ linb, float* __restrict__ x1){
  int wv = threadIdx.x >> 6, lane = threadIdx.x & 63;
  int n = blockIdx.x*4 + wv;
  if (n >= NNODE) return;
  const int st = offs[n], en = st + deg[n];
  const float4 r0 = *(const float4*)(xr1 + n*8);
  const float4 r1 = *(const float4*)(xr1 + n*8 + 4);
  float at0=att[0], at1=att[1], at2=att[2], at3=att[3];
  float at4=att[4], at5=att[5], at6=att[6], at7=att[7];

  float d0=0.f, d1=0.f;
  float n0=0.f,n1=0.f,n2=0.f,n3=0.f,n4=0.f,n5=0.f,n6=0.f,n7=0.f;
  for (int i = st + lane; i < en; i += 64){
    int s = csrc[i];
    const float4 q0 = *(const float4*)(xl1 + s*8);
    const float4 q1 = *(const float4*)(xl1 + s*8 + 4);
    float l0 = at0*lrelu(q0.x+r0.x) + at1*lrelu(q0.y+r0.y)
             + at2*lrelu(q0.z+r0.z) + at3*lrelu(q0.w+r0.w);
    float l1 = at4*lrelu(q1.x+r1.x) + at5*lrelu(q1.y+r1.y)
             + at6*lrelu(q1.z+r1.z) + at7*lrelu(q1.w+r1.w);
    float e0 = expf(l0), e1 = expf(l1);
    d0 += e0; d1 += e1;
    n0 += e0*q0.x; n1 += e0*q0.y; n2 += e0*q0.z; n3 += e0*q0.w;
    n4 += e1*q1.x; n5 += e1*q1.y; n6 += e1*q1.z; n7 += e1*q1.w;
  }
  RED1(d0) RED1(d1)
  RED1(n0) RED1(n1) RED1(n2) RED1(n3)
  RED1(n4) RED1(n5) RED1(n6) RED1(n7)
  if (lane == 0){
    float acc = linb[0];
    acc = fmaf(frelu(n0/d0 + bias1[0]), linW[0], acc);
    acc = fmaf(frelu(n1/d0 + bias1[1]), linW[1], acc);
    acc = fmaf(frelu(n2/d0 + bias1[2]), linW[2], acc);
    acc = fmaf(frelu(n3/d0 + bias1[3]), linW[3], acc);
    acc = fmaf(frelu(n4/d1 + bias1[4]), linW[4], acc);
    acc = fmaf(frelu(n5/d1 + bias1[5]), linW[5], acc);
    acc = fmaf(frelu(n6/d1 + bias1[6]), linW[6], acc);
    acc = fmaf(frelu(n7/d1 + bias1[7]), linW[7], acc);
    x1[n] = acc;
  }
}

// ---------------------------------------------------------------------------
// conv2 aggregation (rank-1: features from scalar x1) + x2 in-register.
__global__ __launch_bounds__(256)
void conv2_agg(const int* __restrict__ offs, const int* __restrict__ deg,
               const int* __restrict__ csrc, const float* __restrict__ x1,
               const float* __restrict__ Wl2, const float* __restrict__ bl2,
               const float* __restrict__ Wr2, const float* __restrict__ br2,
               const float* __restrict__ att, const float* __restrict__ bias2,
               const float* __restrict__ l2W, const float* __restrict__ l2b,
               float* __restrict__ x2a){
  int wv = threadIdx.x >> 6, lane = threadIdx.x & 63;
  int n = blockIdx.x*4 + wv;
  if (n >= NNODE) return;
  const int st = offs[n], en = st + deg[n];
  const float xd = x1[n];
  float wr[8], wl[8], blv[8], atv[8];
  #pragma unroll
  for (int c = 0; c < 8; ++c){
    wr[c]  = fmaf(xd, Wr2[c], br2[c]);
    wl[c]  = Wl2[c];
    blv[c] = bl2[c];
    atv[c] = att[c];
  }
  float d0=0.f, d1=0.f;
  float n0=0.f,n1=0.f,n2=0.f,n3=0.f,n4=0.f,n5=0.f,n6=0.f,n7=0.f;
  for (int i = st + lane; i < en; i += 64){
    float xs = x1[csrc[i]];
    float f0 = fmaf(xs, wl[0], blv[0]);
    float f1 = fmaf(xs, wl[1], blv[1]);
    float f2 = fmaf(xs, wl[2], blv[2]);
    float f3 = fmaf(xs, wl[3], blv[3]);
    float f4 = fmaf(xs, wl[4], blv[4]);
    float f5 = fmaf(xs, wl[5], blv[5]);
    float f6 = fmaf(xs, wl[6], blv[6]);
    float f7 = fmaf(xs, wl[7], blv[7]);
    float l0 = atv[0]*lrelu(f0+wr[0]) + atv[1]*lrelu(f1+wr[1])
             + atv[2]*lrelu(f2+wr[2]) + atv[3]*lrelu(f3+wr[3]);
    float l1 = atv[4]*lrelu(f4+wr[4]) + atv[5]*lrelu(f5+wr[5])
             + atv[6]*lrelu(f6+wr[6]) + atv[7]*lrelu(f7+wr[7]);
    float e0 = expf(l0), e1 = expf(l1);
    d0 += e0; d1 += e1;
    n0 += e0*f0; n1 += e0*f1; n2 += e0*f2; n3 += e0*f3;
    n4 += e1*f4; n5 += e1*f5; n6 += e1*f6; n7 += e1*f7;
  }
  RED1(d0) RED1(d1)
  RED1(n0) RED1(n1) RED1(n2) RED1(n3)
  RED1(n4) RED1(n5) RED1(n6) RED1(n7)
  if (lane == 0){
    float acc = l2b[0];
    acc = fmaf(frelu(n0/d0 + bias2[0]), l2W[0], acc);
    acc = fmaf(frelu(n1/d0 + bias2[1]), l2W[1], acc);
    acc = fmaf(frelu(n2/d0 + bias2[2]), l2W[2], acc);
    acc = fmaf(frelu(n3/d0 + bias2[3]), l2W[3], acc);
    acc = fmaf(frelu(n4/d1 + bias2[4]), l2W[4], acc);
    acc = fmaf(frelu(n5/d1 + bias2[5]), l2W[5], acc);
    acc = fmaf(frelu(n6/d1 + bias2[6]), l2W[6], acc);
    acc = fmaf(frelu(n7/d1 + bias2[7]), l2W[7], acc);
    x2a[n] = acc;
  }
}

// ---------------------------------------------------------------------------
// h1 = relu(encp + x1*W1[9998] + x2*W1[9999] + b1); h2 = relu(h1@W2+b2);
// out = h2@W3 + b3.  One node per wave.
__global__ void enc_finish(const float* __restrict__ encp, const float* __restrict__ x1,
                           const float* __restrict__ x2a,
                           const float* __restrict__ W1, const float* __restrict__ b1,
                           const float* __restrict__ W2, const float* __restrict__ b2,
                           const float* __restrict__ W3, const float* __restrict__ b3,
                           float* __restrict__ out){
  __shared__ float hb[4][64];
  int wv = threadIdx.x >> 6, lane = threadIdx.x & 63;
  int n = blockIdx.x*4 + wv;
  float hv = encp[n*64 + lane] + x1[n]*W1[9998*64 + lane]
           + x2a[n]*W1[9999*64 + lane] + b1[lane];
  hb[wv][lane] = frelu(hv);
  __syncthreads();
  float t = 0.f;
  if (lane < 32) {
    float a2 = b2[lane];
    #pragma unroll
    for (int k = 0; k < 64; ++k) a2 = fmaf(hb[wv][k], W2[k*32 + lane], a2);
    t = frelu(a2) * W3[lane];
  }
  #pragma unroll
  for (int m = 1; m < 64; m <<= 1) t += __shfl_xor(t, m, 64);
  if (lane == 0) out[n] = t + b3[0];
}

// ---------------------------------------------------------------------------
extern "C" void kernel_launch(void* const* d_in, const int* in_sizes, int n_in,
                              void* d_out, int out_size, void* d_ws, size_t ws_size,
                              hipStream_t stream){
  (void)in_sizes; (void)n_in; (void)out_size; (void)ws_size;
  const float* x    = (const float*)d_in[0];
  const int*   ei   = (const int*)  d_in[1];
  const float* Wl1  = (const float*)d_in[2];
  const float* bl1  = (const float*)d_in[3];
  const float* Wr1  = (const float*)d_in[4];
  const float* br1  = (const float*)d_in[5];
  const float* att1 = (const float*)d_in[6];
  const float* bias1= (const float*)d_in[7];
  const float* l1W  = (const float*)d_in[8];
  const float* l1b  = (const float*)d_in[9];
  const float* Wl2  = (const float*)d_in[10];
  const float* bl2  = (const float*)d_in[11];
  const float* Wr2  = (const float*)d_in[12];
  const float* br2  = (const float*)d_in[13];
  const float* att2 = (const float*)d_in[14];
  const float* bias2= (const float*)d_in[15];
  const float* l2W  = (const float*)d_in[16];
  const float* l2b  = (const float*)d_in[17];
  const float* eW1  = (const float*)d_in[18];
  const float* eb1  = (const float*)d_in[19];
  const float* eW2  = (const float*)d_in[20];
  const float* eb2  = (const float*)d_in[21];
  const float* eW3  = (const float*)d_in[22];
  const float* eb3  = (const float*)d_in[23];

  float* ws = (float*)d_ws;
  size_t off = 0;
  auto alloc = [&](size_t nel){ float* pp = ws + off; off += (nel + 63) & ~size_t(63); return pp; };
  _Float16* Wpad  = (_Float16*)alloc((size_t)KSL*WSLH/2);
  _Float16* slabh = (_Float16*)alloc((size_t)20*NSLAB/2);   // 32 MB
  float* xl1    = alloc(NNODE*8);
  float* xr1    = alloc(NNODE*8);
  float* encp   = alloc(NNODE*64);
  float* x1a    = alloc(NNODE);
  float* x2a    = alloc(NNODE);
  // int block [deg(10048), cnt(10048)] zeroed by prep_wt every launch:
  int*   deg    = (int*)alloc(NNODE);
  int*   cnt    = (int*)alloc(NNODE);
  int*   offs   = (int*)alloc(NNODE);
  int*   csrc   = (int*)alloc(NEDGE + NNODE);

  const int ET = NEDGE + NNODE;
  const int eb = (ET + 255)/256;

  prep_wt<<<(KSL*WSLH + 255)/256, 256, 0, stream>>>(Wl1, Wr1, eW1, Wpad, deg);

  k1_fused<<<157*20, 256, 0, stream>>>(x, Wpad, slabh);
  reduce80<<<(NSLAB + 255)/256, 256, 0, stream>>>(slabh, bl1, br1, xl1, xr1, encp);

  csr_hist<<<eb, 256, 0, stream>>>(ei, deg);
  csr_scan<<<1, 256, 0, stream>>>(deg, offs);
  csr_scat<<<eb, 256, 0, stream>>>(ei, offs, cnt, csrc);

  conv1_agg<<<(NNODE + 3)/4, 256, 0, stream>>>(offs, deg, csrc, xl1, xr1, att1,
                                               bias1, l1W, l1b, x1a);
  conv2_agg<<<(NNODE + 3)/4, 256, 0, stream>>>(offs, deg, csrc, x1a, Wl2, bl2,
                                               Wr2, br2, att2, bias2, l2W, l2b, x2a);

  enc_finish<<<NNODE/4, 256, 0, stream>>>(encp, x1a, x2a, eW1, eb1, eW2, eb2,
                                          eW3, eb3, (float*)d_out);
}

// Round 17
// 217.723 us; speedup vs baseline: 7.5852x; 1.0092x over previous
//
#include <hip/hip_runtime.h>
#include <math.h>

#define NNODE 10000
#define INCH  9998
#define NEDGE 320000
#define KSL   40           // K-slices of 256 (ks 0..39); k1 block does ks=j, j+20
#define WCOL  264          // padded k-stride of W slice (halves)
#define WSLH  21120        // halves per W slice: 80*264 (42240 B)
#define NSLAB 800000       // values per output slab (10000 x 80)
#define ZNI   20096        // ints zeroed: [deg(10048), cnt(10048)]

typedef _Float16 half8 __attribute__((ext_vector_type(8)));
typedef float    f32x4 __attribute__((ext_vector_type(4)));

__device__ __forceinline__ float lrelu(float v){ return v > 0.f ? v : 0.2f*v; }
__device__ __forceinline__ float frelu(float v){ return v > 0.f ? v : 0.f; }

#define RED1(v) { _Pragma("unroll") for (int m_ = 1; m_ < 64; m_ <<= 1) v += __shfl_xor(v, m_, 64); }

// ---------------------------------------------------------------------------
// Weight prep (unchanged): Wpad[ks][col][kk] fp16; zero-inits CSR counters.
__global__ void prep_wt(const float* __restrict__ Wl, const float* __restrict__ Wr,
                        const float* __restrict__ We, _Float16* __restrict__ Wpad,
                        int* __restrict__ zint){
  int idx = blockIdx.x*256 + threadIdx.x;
  if (idx < ZNI) zint[idx] = 0;
  if (idx >= KSL*WSLH) return;
  int ks  = idx / WSLH;
  int rem = idx - ks*WSLH;
  int col = rem / WCOL;
  int kk  = rem - col*WCOL;
  int k   = ks*256 + kk;
  float v = 0.f;
  if (kk < 256 && k < INCH)
    v = (col < 8) ? Wl[k*8 + col] : (col < 16 ? Wr[k*8 + (col-8)] : We[k*64 + (col-16)]);
  Wpad[idx] = (_Float16)v;
}

// ---------------------------------------------------------------------------
// k1 (r15 structure, PROVEN). r17 change: x loads 4x float2 -> 2x 16B memcpy
// (global_load_dwordx4 @ 4B align via unaligned-access mode) — halves the
// per-chunk VMEM line-request count (the measured wall since r14).
#define XL(C, X0, X1) { \
  int kb_ = k0b + (C)*32 + 8*g; \
  __builtin_memcpy(&X0, x + min(xbase + kb_    , maxi4), 16); \
  __builtin_memcpy(&X1, x + min(xbase + kb_ + 4, maxi4), 16); }

#define CMP(C, X0, X1) { \
  half8 ah = {(_Float16)X0.x, (_Float16)X0.y, (_Float16)X0.z, (_Float16)X0.w, \
              (_Float16)X1.x, (_Float16)X1.y, (_Float16)X1.z, (_Float16)X1.w}; \
  const _Float16* wp_ = lw + (C)*32 + 8*g; \
  half8 b0 = *(const half8*)(wp_ + (c0     )*WCOL); \
  half8 b1 = *(const half8*)(wp_ + (c0 + 16)*WCOL); \
  half8 b2 = *(const half8*)(wp_ + (c0 + 32)*WCOL); \
  half8 b3 = *(const half8*)(wp_ + (c0 + 48)*WCOL); \
  half8 b4 = *(const half8*)(wp_ + (c0 + 64)*WCOL); \
  a0 = __builtin_amdgcn_mfma_f32_16x16x32_f16(ah, b0, a0, 0, 0, 0); \
  a1 = __builtin_amdgcn_mfma_f32_16x16x32_f16(ah, b1, a1, 0, 0, 0); \
  a2 = __builtin_amdgcn_mfma_f32_16x16x32_f16(ah, b2, a2, 0, 0, 0); \
  a3 = __builtin_amdgcn_mfma_f32_16x16x32_f16(ah, b3, a3, 0, 0, 0); \
  a4 = __builtin_amdgcn_mfma_f32_16x16x32_f16(ah, b4, a4, 0, 0, 0); }

__global__ __launch_bounds__(256, 3)
void k1_fused(const float* __restrict__ x, const _Float16* __restrict__ Wpad,
              _Float16* __restrict__ slabh){
  __shared__ _Float16 lw[WSLH];
  const int tid  = threadIdx.x;
  const int lane = tid & 63;
  const int wv   = tid >> 6;
  const int g    = lane >> 4;
  const int c0   = lane & 15;
  const int bid  = blockIdx.x;
  const int j    = bid / 157;           // output slab 0..19
  const int rb   = bid - j*157;         // row block 0..156
  const int arow = rb*64 + wv*16 + c0;
  const int xbase= (arow < NNODE ? arow : NNODE-1)*INCH;
  const int maxi4= NNODE*INCH - 4;

  f32x4 a0={0,0,0,0}, a1={0,0,0,0}, a2={0,0,0,0}, a3={0,0,0,0}, a4={0,0,0,0};

  for (int h = 0; h < 2; ++h){
    const int ks  = j + 20*h;
    const int k0b = ks << 8;
    if (h) __syncthreads();
    {
      const uint4* src = (const uint4*)(Wpad + (size_t)ks*WSLH);
      uint4* dst = (uint4*)lw;
      #pragma unroll
      for (int i = 0; i < 11; ++i){
        int idx = tid + 256*i;
        if (idx < 2640) dst[idx] = src[idx];
      }
    }
    __syncthreads();

    f32x4 xa0, xa1, xb0, xb1;
    XL(0, xa0, xa1)
    #pragma unroll
    for (int c = 0; c < 8; c += 2){     // 2-slot static pipeline (no reg moves)
      XL(c+1, xb0, xb1)
      CMP(c,   xa0, xa1)
      if (c + 2 < 8) XL(c+2, xa0, xa1)
      CMP(c+1, xb0, xb1)
    }
  }

  // epilogue: C/D layout col=lane&15, row=4*(lane>>4)+reg [m89-verified]
  const int nodeb = rb*64 + wv*16 + 4*g;
  #define EPI(T, A) { \
    _Pragma("unroll") \
    for (int r = 0; r < 4; ++r){ \
      int row = nodeb + r; \
      if (row < NNODE) \
        slabh[(size_t)j*NSLAB + (size_t)row*80 + 16*(T) + c0] = (_Float16)A[r]; \
    } }
  EPI(0, a0) EPI(1, a1) EPI(2, a2) EPI(3, a3) EPI(4, a4)
}

// ---------------------------------------------------------------------------
__global__ void reduce80(const _Float16* __restrict__ slabh, const float* __restrict__ bl1,
                         const float* __restrict__ br1, float* __restrict__ xl1,
                         float* __restrict__ xr1, float* __restrict__ encp){
  int f = blockIdx.x*256 + threadIdx.x;
  if (f >= NSLAB) return;
  float s = 0.f;
  #pragma unroll
  for (int k = 0; k < 20; ++k) s += (float)slabh[(size_t)k*NSLAB + f];
  int n = f / 80;
  int col = f - n*80;
  if (col < 8)       xl1[n*8 + col]        = s + bl1[col];
  else if (col < 16) xr1[n*8 + col - 8]    = s + br1[col - 8];
  else               encp[n*64 + col - 16] = s;
}

// ---------------------------------------------------------------------------
// CSR build (dst-grouped edge list incl. self-loops). deg/cnt pre-zeroed.
__global__ void csr_hist(const int* __restrict__ ei, int* __restrict__ deg){
  int e = blockIdx.x*256 + threadIdx.x;
  if (e >= NEDGE + NNODE) return;
  int d = (e < NEDGE) ? ei[NEDGE + e] : e - NEDGE;
  atomicAdd(deg + d, 1);
}

__global__ void csr_scan(const int* __restrict__ deg, int* __restrict__ offs){
  __shared__ int ssum[256];
  int t = threadIdx.x;
  int base = t*40;
  int s = 0;
  for (int i = 0; i < 40; ++i){
    int idx = base + i;
    s += (idx < NNODE) ? deg[idx] : 0;
  }
  ssum[t] = s;
  __syncthreads();
  for (int d = 1; d < 256; d <<= 1){
    int v = (t >= d) ? ssum[t - d] : 0;
    __syncthreads();
    ssum[t] += v;
    __syncthreads();
  }
  int run = (t == 0) ? 0 : ssum[t - 1];
  for (int i = 0; i < 40; ++i){
    int idx = base + i;
    if (idx < NNODE){ offs[idx] = run; run += deg[idx]; }
  }
}

__global__ void csr_scat(const int* __restrict__ ei, const int* __restrict__ offs,
                         int* __restrict__ cnt, int* __restrict__ csrc){
  int e = blockIdx.x*256 + threadIdx.x;
  if (e >= NEDGE + NNODE) return;
  int s, d;
  if (e < NEDGE){ s = ei[e]; d = ei[NEDGE + e]; } else { s = d = e - NEDGE; }
  int p = offs[d] + atomicAdd(cnt + d, 1);
  csrc[p] = s;
}

// ---------------------------------------------------------------------------
// conv1 aggregation, wave-per-dst, ONE pass, NO atomics.
__global__ __launch_bounds__(256)
void conv1_agg(const int* __restrict__ offs, const int* __restrict__ deg,
               const int* __restrict__ csrc, const float* __restrict__ xl1,
               const float* __restrict__ xr1, const float* __restrict__ att,
               const float* __restrict__ bias1, const float* __restrict__ linW,
               const float* __restrict__ linb, float* __restrict__ x1){
  int wv = threadIdx.x >> 6, lane = threadIdx.x & 63;
  int n = blockIdx.x*4 + wv;
  if (n >= NNODE) return;
  const int st = offs[n], en = st + deg[n];
  const float4 r0 = *(const float4*)(xr1 + n*8);
  const float4 r1 = *(const float4*)(xr1 + n*8 + 4);
  float at0=att[0], at1=att[1], at2=att[2], at3=att[3];
  float at4=att[4], at5=att[5], at6=att[6], at7=att[7];

  float d0=0.f, d1=0.f;
  float n0=0.f,n1=0.f,n2=0.f,n3=0.f,n4=0.f,n5=0.f,n6=0.f,n7=0.f;
  for (int i = st + lane; i < en; i += 64){
    int s = csrc[i];
    const float4 q0 = *(const float4*)(xl1 + s*8);
    const float4 q1 = *(const float4*)(xl1 + s*8 + 4);
    float l0 = at0*lrelu(q0.x+r0.x) + at1*lrelu(q0.y+r0.y)
             + at2*lrelu(q0.z+r0.z) + at3*lrelu(q0.w+r0.w);
    float l1 = at4*lrelu(q1.x+r1.x) + at5*lrelu(q1.y+r1.y)
             + at6*lrelu(q1.z+r1.z) + at7*lrelu(q1.w+r1.w);
    float e0 = expf(l0), e1 = expf(l1);
    d0 += e0; d1 += e1;
    n0 += e0*q0.x; n1 += e0*q0.y; n2 += e0*q0.z; n3 += e0*q0.w;
    n4 += e1*q1.x; n5 += e1*q1.y; n6 += e1*q1.z; n7 += e1*q1.w;
  }
  RED1(d0) RED1(d1)
  RED1(n0) RED1(n1) RED1(n2) RED1(n3)
  RED1(n4) RED1(n5) RED1(n6) RED1(n7)
  if (lane == 0){
    float acc = linb[0];
    acc = fmaf(frelu(n0/d0 + bias1[0]), linW[0], acc);
    acc = fmaf(frelu(n1/d0 + bias1[1]), linW[1], acc);
    acc = fmaf(frelu(n2/d0 + bias1[2]), linW[2], acc);
    acc = fmaf(frelu(n3/d0 + bias1[3]), linW[3], acc);
    acc = fmaf(frelu(n4/d1 + bias1[4]), linW[4], acc);
    acc = fmaf(frelu(n5/d1 + bias1[5]), linW[5], acc);
    acc = fmaf(frelu(n6/d1 + bias1[6]), linW[6], acc);
    acc = fmaf(frelu(n7/d1 + bias1[7]), linW[7], acc);
    x1[n] = acc;
  }
}

// ---------------------------------------------------------------------------
// conv2 aggregation (rank-1 from scalar x1) + x2 in-register.
__global__ __launch_bounds__(256)
void conv2_agg(const int* __restrict__ offs, const int* __restrict__ deg,
               const int* __restrict__ csrc, const float* __restrict__ x1,
               const float* __restrict__ Wl2, const float* __restrict__ bl2,
               const float* __restrict__ Wr2, const float* __restrict__ br2,
               const float* __restrict__ att, const float* __restrict__ bias2,
               const float* __restrict__ l2W, const float* __restrict__ l2b,
               float* __restrict__ x2a){
  int wv = threadIdx.x >> 6, lane = threadIdx.x & 63;
  int n = blockIdx.x*4 + wv;
  if (n >= NNODE) return;
  const int st = offs[n], en = st + deg[n];
  const float xd = x1[n];
  float wr[8], wl[8], blv[8], atv[8];
  #pragma unroll
  for (int c = 0; c < 8; ++c){
    wr[c]  = fmaf(xd, Wr2[c], br2[c]);
    wl[c]  = Wl2[c];
    blv[c] = bl2[c];
    atv[c] = att[c];
  }
  float d0=0.f, d1=0.f;
  float n0=0.f,n1=0.f,n2=0.f,n3=0.f,n4=0.f,n5=0.f,n6=0.f,n7=0.f;
  for (int i = st + lane; i < en; i += 64){
    float xs = x1[csrc[i]];
    float f0 = fmaf(xs, wl[0], blv[0]);
    float f1 = fmaf(xs, wl[1], blv[1]);
    float f2 = fmaf(xs, wl[2], blv[2]);
    float f3 = fmaf(xs, wl[3], blv[3]);
    float f4 = fmaf(xs, wl[4], blv[4]);
    float f5 = fmaf(xs, wl[5], blv[5]);
    float f6 = fmaf(xs, wl[6], blv[6]);
    float f7 = fmaf(xs, wl[7], blv[7]);
    float l0 = atv[0]*lrelu(f0+wr[0]) + atv[1]*lrelu(f1+wr[1])
             + atv[2]*lrelu(f2+wr[2]) + atv[3]*lrelu(f3+wr[3]);
    float l1 = atv[4]*lrelu(f4+wr[4]) + atv[5]*lrelu(f5+wr[5])
             + atv[6]*lrelu(f6+wr[6]) + atv[7]*lrelu(f7+wr[7]);
    float e0 = expf(l0), e1 = expf(l1);
    d0 += e0; d1 += e1;
    n0 += e0*f0; n1 += e0*f1; n2 += e0*f2; n3 += e0*f3;
    n4 += e1*f4; n5 += e1*f5; n6 += e1*f6; n7 += e1*f7;
  }
  RED1(d0) RED1(d1)
  RED1(n0) RED1(n1) RED1(n2) RED1(n3)
  RED1(n4) RED1(n5) RED1(n6) RED1(n7)
  if (lane == 0){
    float acc = l2b[0];
    acc = fmaf(frelu(n0/d0 + bias2[0]), l2W[0], acc);
    acc = fmaf(frelu(n1/d0 + bias2[1]), l2W[1], acc);
    acc = fmaf(frelu(n2/d0 + bias2[2]), l2W[2], acc);
    acc = fmaf(frelu(n3/d0 + bias2[3]), l2W[3], acc);
    acc = fmaf(frelu(n4/d1 + bias2[4]), l2W[4], acc);
    acc = fmaf(frelu(n5/d1 + bias2[5]), l2W[5], acc);
    acc = fmaf(frelu(n6/d1 + bias2[6]), l2W[6], acc);
    acc = fmaf(frelu(n7/d1 + bias2[7]), l2W[7], acc);
    x2a[n] = acc;
  }
}

// ---------------------------------------------------------------------------
__global__ void enc_finish(const float* __restrict__ encp, const float* __restrict__ x1,
                           const float* __restrict__ x2a,
                           const float* __restrict__ W1, const float* __restrict__ b1,
                           const float* __restrict__ W2, const float* __restrict__ b2,
                           const float* __restrict__ W3, const float* __restrict__ b3,
                           float* __restrict__ out){
  __shared__ float hb[4][64];
  int wv = threadIdx.x >> 6, lane = threadIdx.x & 63;
  int n = blockIdx.x*4 + wv;
  float hv = encp[n*64 + lane] + x1[n]*W1[9998*64 + lane]
           + x2a[n]*W1[9999*64 + lane] + b1[lane];
  hb[wv][lane] = frelu(hv);
  __syncthreads();
  float t = 0.f;
  if (lane < 32) {
    float a2 = b2[lane];
    #pragma unroll
    for (int k = 0; k < 64; ++k) a2 = fmaf(hb[wv][k], W2[k*32 + lane], a2);
    t = frelu(a2) * W3[lane];
  }
  #pragma unroll
  for (int m = 1; m < 64; m <<= 1) t += __shfl_xor(t, m, 64);
  if (lane == 0) out[n] = t + b3[0];
}

// ---------------------------------------------------------------------------
extern "C" void kernel_launch(void* const* d_in, const int* in_sizes, int n_in,
                              void* d_out, int out_size, void* d_ws, size_t ws_size,
                              hipStream_t stream){
  (void)in_sizes; (void)n_in; (void)out_size; (void)ws_size;
  const float* x    = (const float*)d_in[0];
  const int*   ei   = (const int*)  d_in[1];
  const float* Wl1  = (const float*)d_in[2];
  const float* bl1  = (const float*)d_in[3];
  const float* Wr1  = (const float*)d_in[4];
  const float* br1  = (const float*)d_in[5];
  const float* att1 = (const float*)d_in[6];
  const float* bias1= (const float*)d_in[7];
  const float* l1W  = (const float*)d_in[8];
  const float* l1b  = (const float*)d_in[9];
  const float* Wl2  = (const float*)d_in[10];
  const float* bl2  = (const float*)d_in[11];
  const float* Wr2  = (const float*)d_in[12];
  const float* br2  = (const float*)d_in[13];
  const float* att2 = (const float*)d_in[14];
  const float* bias2= (const float*)d_in[15];
  const float* l2W  = (const float*)d_in[16];
  const float* l2b  = (const float*)d_in[17];
  const float* eW1  = (const float*)d_in[18];
  const float* eb1  = (const float*)d_in[19];
  const float* eW2  = (const float*)d_in[20];
  const float* eb2  = (const float*)d_in[21];
  const float* eW3  = (const float*)d_in[22];
  const float* eb3  = (const float*)d_in[23];

  float* ws = (float*)d_ws;
  size_t off = 0;
  auto alloc = [&](size_t nel){ float* pp = ws + off; off += (nel + 63) & ~size_t(63); return pp; };
  _Float16* Wpad  = (_Float16*)alloc((size_t)KSL*WSLH/2);
  _Float16* slabh = (_Float16*)alloc((size_t)20*NSLAB/2);   // 32 MB
  float* xl1    = alloc(NNODE*8);
  float* xr1    = alloc(NNODE*8);
  float* encp   = alloc(NNODE*64);
  float* x1a    = alloc(NNODE);
  float* x2a    = alloc(NNODE);
  // int block [deg(10048), cnt(10048)] zeroed by prep_wt every launch:
  int*   deg    = (int*)alloc(NNODE);
  int*   cnt    = (int*)alloc(NNODE);
  int*   offs   = (int*)alloc(NNODE);
  int*   csrc   = (int*)alloc(NEDGE + NNODE);

  const int ET = NEDGE + NNODE;
  const int eb = (ET + 255)/256;

  prep_wt<<<(KSL*WSLH + 255)/256, 256, 0, stream>>>(Wl1, Wr1, eW1, Wpad, deg);

  k1_fused<<<157*20, 256, 0, stream>>>(x, Wpad, slabh);
  reduce80<<<(NSLAB + 255)/256, 256, 0, stream>>>(slabh, bl1, br1, xl1, xr1, encp);

  csr_hist<<<eb, 256, 0, stream>>>(ei, deg);
  csr_scan<<<1, 256, 0, stream>>>(deg, offs);
  csr_scat<<<eb, 256, 0, stream>>>(ei, offs, cnt, csrc);

  conv1_agg<<<(NNODE + 3)/4, 256, 0, stream>>>(offs, deg, csrc, xl1, xr1, att1,
                                               bias1, l1W, l1b, x1a);
  conv2_agg<<<(NNODE + 3)/4, 256, 0, stream>>>(offs, deg, csrc, x1a, Wl2, bl2,
                                               Wr2, br2, att2, bias2, l2W, l2b, x2a);

  enc_finish<<<NNODE/4, 256, 0, stream>>>(encp, x1a, x2a, eW1, eb1, eW2, eb2,
                                          eW3, eb3, (float*)d_out);
}